// Round 1
// baseline (580.306 us; speedup 1.0000x reference)
//
#include <hip/hip_runtime.h>
#include <math.h>

// ============================================================================
// TransformerEncoder_gram: fused multimodal gram-determinant attention.
// Strategy: split-bf16 (hi+lo) MFMA GEMMs for fp32-class precision where the
// near-argmax softmax demands it; flash-style fused attention (no SxS buffer).
// Workspace use: ~211 MB.
// ============================================================================

typedef short bf16x8 __attribute__((ext_vector_type(8)));
typedef float f32x4  __attribute__((ext_vector_type(4)));
typedef float f32x4g __attribute__((ext_vector_type(4)));

#define MFMA16(a,b,c) __builtin_amdgcn_mfma_f32_16x16x32_bf16((a),(b),(c),0,0,0)

static constexpr float LOG2E_F = 1.4426950408889634f;

__device__ __forceinline__ float b2f(unsigned short s){
  union { unsigned u; float f; } v; v.u = ((unsigned)s) << 16; return v.f;
}
__device__ __forceinline__ unsigned short f2b(float f){
  union { float f; unsigned u; } v; v.f = f;
  unsigned r = v.u + 0x7fffu + ((v.u >> 16) & 1u);
  return (unsigned short)(r >> 16);
}

// ---------------------------------------------------------------------------
// split fp32 -> (hi, lo) bf16 pair;  x = hi + lo to ~2^-17 relative.
// ---------------------------------------------------------------------------
__global__ __launch_bounds__(256) void split_kernel(
    const float* __restrict__ x, unsigned short* __restrict__ hi,
    unsigned short* __restrict__ lo, int n)
{
  int stride = gridDim.x * 256;
  for (int i = blockIdx.x*256 + threadIdx.x; i < n; i += stride){
    float v = x[i];
    unsigned short h = f2b(v);
    hi[i] = h;
    lo[i] = f2b(v - b2f(h));
  }
}

// ---------------------------------------------------------------------------
// Split-bf16 GEMM:  C(r,e) = sum_c A(r,c)*B(e,c)   (NT form, K-contiguous)
// M=8192, N=512, K=512.  Tile 64x64, BK=32, 4 waves (16 rows each).
// NPASS: 3 = AhiBhi+AhiBlo+AloBhi (fp32-class), 1 = AhiBhi (bf16-class).
// EPI: 0 = fp32 [r][e] (+bias)*scale;  1 = head-split bf16 hi/lo [bh][t][d].
// ---------------------------------------------------------------------------
template<int NPASS, int EPI>
__global__ __launch_bounds__(256) void gemm_split_kernel(
    const unsigned short* __restrict__ Ahi, const unsigned short* __restrict__ Alo,
    const unsigned short* __restrict__ Bhi, const unsigned short* __restrict__ Blo,
    const float* __restrict__ bias, float scale,
    float* __restrict__ outF,
    unsigned short* __restrict__ outHi, unsigned short* __restrict__ outLo)
{
  __shared__ unsigned short sAhi[64*32];
  __shared__ unsigned short sAlo[64*32];
  __shared__ unsigned short sBhi[64*32];
  __shared__ unsigned short sBlo[64*32];
  const int tid = threadIdx.x, w = tid >> 6, lane = tid & 63;
  const int r0 = blockIdx.x * 64, e0 = blockIdx.y * 64;
  f32x4 acc[4];
  #pragma unroll
  for (int i = 0; i < 4; ++i) acc[i] = (f32x4){0.f,0.f,0.f,0.f};
  const int srow = tid >> 2, ssl = tid & 3;              // staging row / 16B slot
  const size_t aOff = (size_t)(r0 + srow)*512 + ssl*8;
  const size_t bOff = (size_t)(e0 + srow)*512 + ssl*8;
  const int sAddr = srow*32 + ssl*8;
  const int arow = w*16 + (lane & 15);
  const int kg = lane >> 4;

  for (int kk = 0; kk < 512; kk += 32){
    *(bf16x8*)&sAhi[sAddr] = *(const bf16x8*)&Ahi[aOff + kk];
    if constexpr (NPASS == 3) *(bf16x8*)&sAlo[sAddr] = *(const bf16x8*)&Alo[aOff + kk];
    *(bf16x8*)&sBhi[sAddr] = *(const bf16x8*)&Bhi[bOff + kk];
    if constexpr (NPASS >= 2) *(bf16x8*)&sBlo[sAddr] = *(const bf16x8*)&Blo[bOff + kk];
    __syncthreads();
    bf16x8 ahi = *(const bf16x8*)&sAhi[arow*32 + kg*8];
    bf16x8 alo;
    if constexpr (NPASS == 3) alo = *(const bf16x8*)&sAlo[arow*32 + kg*8];
    #pragma unroll
    for (int nt = 0; nt < 4; ++nt){
      const int brow = nt*16 + (lane & 15);
      bf16x8 bhi = *(const bf16x8*)&sBhi[brow*32 + kg*8];
      acc[nt] = MFMA16(ahi, bhi, acc[nt]);
      if constexpr (NPASS >= 2){
        bf16x8 blo = *(const bf16x8*)&sBlo[brow*32 + kg*8];
        acc[nt] = MFMA16(ahi, blo, acc[nt]);
      }
      if constexpr (NPASS == 3)
        acc[nt] = MFMA16(alo, bhi, acc[nt]);
    }
    __syncthreads();
  }

  #pragma unroll
  for (int nt = 0; nt < 4; ++nt){
    const int e = e0 + nt*16 + (lane & 15);
    const float bv = bias[e];
    #pragma unroll
    for (int q = 0; q < 4; ++q){
      const int rr = r0 + w*16 + (lane >> 4)*4 + q;   // D row = (lane>>4)*4+reg
      float y = (acc[nt][q] + bv) * scale;
      if constexpr (EPI == 0){
        outF[(size_t)rr*512 + e] = y;
      } else {
        // (T,B,E) row rr=(t*B+b), col e=(h*64+d)  ->  [bh=b*8+h][t][d]
        const int bh = ((rr & 7) << 3) + (e >> 6);
        const size_t off = ((size_t)bh*1024 + (rr >> 3))*64 + (e & 63);
        unsigned short h = f2b(y);
        outHi[off] = h;
        outLo[off] = f2b(y - b2f(h));
      }
    }
  }
}

// ---------------------------------------------------------------------------
// Per-(bh,t) gram scalars: ll=|q|^2, vv=|k1|^2, aa=|k2|^2, va=k1.k2  (fp32)
// ---------------------------------------------------------------------------
__global__ __launch_bounds__(256) void norms_kernel(
    const unsigned short* __restrict__ qh, const unsigned short* __restrict__ ql,
    const unsigned short* __restrict__ k1h, const unsigned short* __restrict__ k1l,
    const unsigned short* __restrict__ k2h, const unsigned short* __restrict__ k2l,
    float* __restrict__ ll, float* __restrict__ vv,
    float* __restrict__ aa, float* __restrict__ va)
{
  const int idx = blockIdx.x*256 + threadIdx.x;        // bh*1024 + t
  const size_t base = (size_t)idx * 64;
  float sll = 0.f, svv = 0.f, saa = 0.f, sva = 0.f;
  #pragma unroll
  for (int j = 0; j < 8; ++j){
    bf16x8 q_h = *(const bf16x8*)&qh[base + j*8];
    bf16x8 q_l = *(const bf16x8*)&ql[base + j*8];
    bf16x8 a_h = *(const bf16x8*)&k1h[base + j*8];
    bf16x8 a_l = *(const bf16x8*)&k1l[base + j*8];
    bf16x8 c_h = *(const bf16x8*)&k2h[base + j*8];
    bf16x8 c_l = *(const bf16x8*)&k2l[base + j*8];
    #pragma unroll
    for (int i = 0; i < 8; ++i){
      float qv = b2f((unsigned short)q_h[i]) + b2f((unsigned short)q_l[i]);
      float a1 = b2f((unsigned short)a_h[i]) + b2f((unsigned short)a_l[i]);
      float a2 = b2f((unsigned short)c_h[i]) + b2f((unsigned short)c_l[i]);
      sll += qv*qv; svv += a1*a1; saa += a2*a2; sva += a1*a2;
    }
  }
  ll[idx] = sll; vv[idx] = svv; aa[idx] = saa; va[idx] = sva;
}

// ---------------------------------------------------------------------------
// v = v1*sig(g1) + v2*sig(g2); write transposed split bf16 vT[bh][d][s]
// block: (s-tile 0..15, bh 0..63)
// ---------------------------------------------------------------------------
__global__ __launch_bounds__(256) void gate_kernel(
    const float* __restrict__ v1, const float* __restrict__ g1,
    const float* __restrict__ v2, const float* __restrict__ g2,
    unsigned short* __restrict__ vTh, unsigned short* __restrict__ vTl)
{
  __shared__ unsigned short sH[64*64];
  __shared__ unsigned short sL[64*64];
  const int bh = blockIdx.y, b = bh >> 3, h = bh & 7;
  const int s0 = blockIdx.x * 64;
  const int tid = threadIdx.x;
  for (int c = tid; c < 1024; c += 256){
    const int i = c >> 4, sl = c & 15;                  // s-offset, 16B col slot
    const size_t g = ((size_t)(s0 + i)*8 + b)*512 + h*64 + sl*4;
    f32x4g a1 = *(const f32x4g*)&v1[g];
    f32x4g b1 = *(const f32x4g*)&g1[g];
    f32x4g a2 = *(const f32x4g*)&v2[g];
    f32x4g b2 = *(const f32x4g*)&g2[g];
    #pragma unroll
    for (int e = 0; e < 4; ++e){
      float s1 = 1.0f / (1.0f + exp2f(-b1[e]*LOG2E_F));
      float s2 = 1.0f / (1.0f + exp2f(-b2[e]*LOG2E_F));
      float v = a1[e]*s1 + a2[e]*s2;
      const int d = sl*4 + e;
      unsigned short hh = f2b(v);
      sH[d*64 + i] = hh;
      sL[d*64 + i] = f2b(v - b2f(hh));
    }
  }
  __syncthreads();
  for (int c = tid; c < 512; c += 256){
    const int d = c >> 3, sl = c & 7;
    const size_t g = ((size_t)bh*64 + d)*1024 + s0 + sl*8;
    *(bf16x8*)&vTh[g] = *(const bf16x8*)&sH[d*64 + sl*8];
    *(bf16x8*)&vTl[g] = *(const bf16x8*)&sL[d*64 + sl*8];
  }
}

// ---------------------------------------------------------------------------
// Fused gram-det attention, flash-style online softmax.
// block = (l-tile 0..15, bh 0..63); 4 waves x 16 L-rows; S-tiles of 64.
// Split-bf16 QK^T (3-pass) and PV (3-pass with split P). XOR-swizzled LDS.
// ---------------------------------------------------------------------------
__global__ __launch_bounds__(256) void attn_kernel(
    const unsigned short* __restrict__ qhh, const unsigned short* __restrict__ qhl,
    const unsigned short* __restrict__ k1hh, const unsigned short* __restrict__ k1hl,
    const unsigned short* __restrict__ k2hh, const unsigned short* __restrict__ k2hl,
    const unsigned short* __restrict__ vTh, const unsigned short* __restrict__ vTl,
    const float* __restrict__ llv, const float* __restrict__ vvv,
    const float* __restrict__ aav, const float* __restrict__ vav,
    unsigned short* __restrict__ aoHi, unsigned short* __restrict__ aoLo)
{
  __shared__ unsigned short sK1h[64*64];
  __shared__ unsigned short sK1l[64*64];
  __shared__ unsigned short sK2h[64*64];
  __shared__ unsigned short sK2l[64*64];
  __shared__ unsigned short sVh[64*64];
  __shared__ unsigned short sVl[64*64];
  __shared__ unsigned short sPh[4*16*64];
  __shared__ unsigned short sPl[4*16*64];
  __shared__ float sNrm[3][64];

  const int bh = blockIdx.y, l0 = blockIdx.x * 64;
  const int tid = threadIdx.x, w = tid >> 6, lane = tid & 63;
  const int lrow = lane & 15, kg = lane >> 4;

  // Q fragments (A operand; m = lane&15), hoisted for the whole kernel.
  bf16x8 qfh[2], qfl[2];
  {
    const size_t qb = ((size_t)bh*1024 + l0 + w*16 + lrow)*64 + kg*8;
    qfh[0] = *(const bf16x8*)&qhh[qb];
    qfl[0] = *(const bf16x8*)&qhl[qb];
    qfh[1] = *(const bf16x8*)&qhh[qb + 32];
    qfl[1] = *(const bf16x8*)&qhl[qb + 32];
  }
  float ll_r[4];
  #pragma unroll
  for (int q = 0; q < 4; ++q)
    ll_r[q] = llv[bh*1024 + l0 + w*16 + kg*4 + q];       // D-row mapping

  f32x4 accO[4];
  #pragma unroll
  for (int i = 0; i < 4; ++i) accO[i] = (f32x4){0.f,0.f,0.f,0.f};
  float m_run[4], s_run[4];
  #pragma unroll
  for (int q = 0; q < 4; ++q){ m_run[q] = -__builtin_inff(); s_run[q] = 0.f; }

  for (int ss = 0; ss < 1024; ss += 64){
    // ---- stage K1/K2/VT tiles (XOR-swizzled 16B slots) + norm slices ----
    for (int c = tid; c < 512; c += 256){
      const int r = c >> 3, sl = c & 7;
      const int la = r*64 + ((sl ^ (r & 7)) * 8);
      const size_t gk = ((size_t)bh*1024 + ss + r)*64 + sl*8;
      *(bf16x8*)&sK1h[la] = *(const bf16x8*)&k1hh[gk];
      *(bf16x8*)&sK1l[la] = *(const bf16x8*)&k1hl[gk];
      *(bf16x8*)&sK2h[la] = *(const bf16x8*)&k2hh[gk];
      *(bf16x8*)&sK2l[la] = *(const bf16x8*)&k2hl[gk];
      const size_t gv = ((size_t)bh*64 + r)*1024 + ss + sl*8;
      *(bf16x8*)&sVh[la] = *(const bf16x8*)&vTh[gv];
      *(bf16x8*)&sVl[la] = *(const bf16x8*)&vTl[gv];
    }
    if (tid < 192){
      const int which = tid >> 6, t_ = tid & 63;
      const float* src = (which == 0) ? vvv : ((which == 1) ? aav : vav);
      sNrm[which][t_] = src[bh*1024 + ss + t_];
    }
    __syncthreads();

    // ---- QK^T: lv = q.k1, la = q.k2 (split-bf16, 3 products each) ----
    f32x4 lv[4], la2[4];
    #pragma unroll
    for (int i = 0; i < 4; ++i){ lv[i] = (f32x4){0.f,0.f,0.f,0.f}; la2[i] = (f32x4){0.f,0.f,0.f,0.f}; }
    #pragma unroll
    for (int nt = 0; nt < 4; ++nt){
      #pragma unroll
      for (int ks = 0; ks < 2; ++ks){
        const int row = nt*16 + lrow;
        const int off = row*64 + (((ks*4 + kg) ^ (row & 7)) * 8);
        bf16x8 b1h = *(const bf16x8*)&sK1h[off];
        bf16x8 b1l = *(const bf16x8*)&sK1l[off];
        bf16x8 b2h = *(const bf16x8*)&sK2h[off];
        bf16x8 b2l = *(const bf16x8*)&sK2l[off];
        lv[nt]  = MFMA16(qfh[ks], b1h, lv[nt]);
        lv[nt]  = MFMA16(qfh[ks], b1l, lv[nt]);
        lv[nt]  = MFMA16(qfl[ks], b1h, lv[nt]);
        la2[nt] = MFMA16(qfh[ks], b2h, la2[nt]);
        la2[nt] = MFMA16(qfh[ks], b2l, la2[nt]);
        la2[nt] = MFMA16(qfl[ks], b2h, la2[nt]);
      }
    }

    // ---- gram det -> score -> online softmax ----
    float p_[4][4];
    float tm[4];
    #pragma unroll
    for (int q = 0; q < 4; ++q) tm[q] = -__builtin_inff();
    #pragma unroll
    for (int nt = 0; nt < 4; ++nt){
      const int scol = nt*16 + lrow;
      const float c_vv = sNrm[0][scol], c_aa = sNrm[1][scol], c_va = sNrm[2][scol];
      const float cross = c_vv*c_aa - c_va*c_va;
      #pragma unroll
      for (int q = 0; q < 4; ++q){
        const float flv = lv[nt][q], fla = la2[nt][q];
        float det = ll_r[q]*cross - flv*(flv*c_aa - fla*c_va)
                                  + fla*(flv*c_va - fla*c_vv);
        float sc = -sqrtf(fmaxf(det, 1e-8f));
        p_[nt][q] = sc;
        tm[q] = fmaxf(tm[q], sc);
      }
    }
    #pragma unroll
    for (int q = 0; q < 4; ++q){
      tm[q] = fmaxf(tm[q], __shfl_xor(tm[q], 1));
      tm[q] = fmaxf(tm[q], __shfl_xor(tm[q], 2));
      tm[q] = fmaxf(tm[q], __shfl_xor(tm[q], 4));
      tm[q] = fmaxf(tm[q], __shfl_xor(tm[q], 8));
    }
    float resc[4], psum[4];
    #pragma unroll
    for (int q = 0; q < 4; ++q){
      const float mn = fmaxf(m_run[q], tm[q]);
      resc[q] = exp2f((m_run[q] - mn) * LOG2E_F);
      m_run[q] = mn;
      psum[q] = 0.f;
    }
    #pragma unroll
    for (int nt = 0; nt < 4; ++nt){
      #pragma unroll
      for (int q = 0; q < 4; ++q){
        const float e = exp2f((p_[nt][q] - m_run[q]) * LOG2E_F);
        p_[nt][q] = e;
        psum[q] += e;
      }
    }
    #pragma unroll
    for (int q = 0; q < 4; ++q){
      psum[q] += __shfl_xor(psum[q], 1);
      psum[q] += __shfl_xor(psum[q], 2);
      psum[q] += __shfl_xor(psum[q], 4);
      psum[q] += __shfl_xor(psum[q], 8);
      s_run[q] = s_run[q]*resc[q] + psum[q];
    }
    #pragma unroll
    for (int dt = 0; dt < 4; ++dt)
      #pragma unroll
      for (int q = 0; q < 4; ++q)
        accO[dt][q] = accO[dt][q] * resc[q];

    // ---- P -> LDS (split bf16, swizzled for A-frag reads) ----
    #pragma unroll
    for (int nt = 0; nt < 4; ++nt){
      #pragma unroll
      for (int q = 0; q < 4; ++q){
        const int row = kg*4 + q, col = nt*16 + lrow;
        const int off = w*1024 + row*64 + (((col >> 3) ^ (row & 7)) * 8) + (col & 7);
        const float pv = p_[nt][q];
        unsigned short hh = f2b(pv);
        sPh[off] = hh;
        sPl[off] = f2b(pv - b2f(hh));
      }
    }
    // intra-wave LDS dependency: compiler orders ds_write->ds_read on same
    // array and inserts lgkmcnt; P region is private per wave.

    // ---- PV: accO += P * V (3-pass split) ----
    #pragma unroll
    for (int ks = 0; ks < 2; ++ks){
      const int poff = w*1024 + lrow*64 + (((ks*4 + kg) ^ (lrow & 7)) * 8);
      bf16x8 pah = *(const bf16x8*)&sPh[poff];
      bf16x8 pal = *(const bf16x8*)&sPl[poff];
      #pragma unroll
      for (int dt = 0; dt < 4; ++dt){
        const int vrow = dt*16 + lrow;
        const int voff = vrow*64 + (((ks*4 + kg) ^ (vrow & 7)) * 8);
        bf16x8 bvh = *(const bf16x8*)&sVh[voff];
        bf16x8 bvl = *(const bf16x8*)&sVl[voff];
        accO[dt] = MFMA16(pah, bvh, accO[dt]);
        accO[dt] = MFMA16(pah, bvl, accO[dt]);
        accO[dt] = MFMA16(pal, bvh, accO[dt]);
      }
    }
    __syncthreads();   // all waves done with sK/sV before next staging
  }

  // ---- normalize + write attn-out as split bf16 [r=(l*8+b)][e=h*64+d] ----
  const int b = bh >> 3, h = bh & 7;
  #pragma unroll
  for (int dt = 0; dt < 4; ++dt){
    const int d = dt*16 + lrow;
    #pragma unroll
    for (int q = 0; q < 4; ++q){
      const int l = l0 + w*16 + kg*4 + q;
      const float o = accO[dt][q] / s_run[q];
      const size_t off = ((size_t)l*8 + b)*512 + h*64 + d;
      unsigned short hh = f2b(o);
      aoHi[off] = hh;
      aoLo[off] = f2b(o - b2f(hh));
    }
  }
}

// ===========================================================================
extern "C" void kernel_launch(void* const* d_in, const int* in_sizes, int n_in,
                              void* d_out, int out_size, void* d_ws, size_t ws_size,
                              hipStream_t stream)
{
  const float* query = (const float*)d_in[0];
  const float* mod1  = (const float*)d_in[1];
  const float* mod2  = (const float*)d_in[2];
  const float* bq  = (const float*)d_in[4];
  const float* bk1 = (const float*)d_in[6];
  const float* bk2 = (const float*)d_in[8];
  const float* bv1 = (const float*)d_in[10];
  const float* bv2 = (const float*)d_in[12];
  const float* bg1 = (const float*)d_in[14];
  const float* bg2 = (const float*)d_in[16];
  const float* bo  = (const float*)d_in[18];
  const int widx[8] = {3, 5, 7, 9, 11, 13, 15, 17};   // Wq,Wk1,Wk2,Wv1,Wv2,Wg1,Wg2,Wo

  char* p = (char*)d_ws;
  auto take = [&](size_t bytes) -> char* {
    char* r = p; p += (bytes + 255) & ~(size_t)255; return r;
  };
  const size_t XB = (size_t)8192*512*2;   // bf16 input-split buffer
  const size_t WB = (size_t)512*512*2;    // bf16 weight-split buffer
  const size_t HB = (size_t)64*1024*64*2; // bf16 head-layout buffer
  const size_t FB = (size_t)8192*512*4;   // fp32 intermediate
  const size_t NB = (size_t)64*1024*4;    // fp32 norms

  unsigned short* xq_hi = (unsigned short*)take(XB);
  unsigned short* xq_lo = (unsigned short*)take(XB);
  unsigned short* x1_hi = (unsigned short*)take(XB);
  unsigned short* x1_lo = (unsigned short*)take(XB);
  unsigned short* x2_hi = (unsigned short*)take(XB);
  unsigned short* x2_lo = (unsigned short*)take(XB);
  unsigned short *w_hi[8], *w_lo[8];
  for (int i = 0; i < 8; ++i){
    w_hi[i] = (unsigned short*)take(WB);
    w_lo[i] = (unsigned short*)take(WB);
  }
  unsigned short* qh_hi  = (unsigned short*)take(HB);
  unsigned short* qh_lo  = (unsigned short*)take(HB);
  unsigned short* k1h_hi = (unsigned short*)take(HB);
  unsigned short* k1h_lo = (unsigned short*)take(HB);
  unsigned short* k2h_hi = (unsigned short*)take(HB);
  unsigned short* k2h_lo = (unsigned short*)take(HB);
  unsigned short* vT_hi  = (unsigned short*)take(HB);
  unsigned short* vT_lo  = (unsigned short*)take(HB);
  float* v1b = (float*)take(FB);
  float* g1b = (float*)take(FB);
  float* v2b = (float*)take(FB);
  float* g2b = (float*)take(FB);
  unsigned short* ao_hi = (unsigned short*)take(HB);
  unsigned short* ao_lo = (unsigned short*)take(HB);
  float* llv = (float*)take(NB);
  float* vvv = (float*)take(NB);
  float* aav = (float*)take(NB);
  float* vav = (float*)take(NB);

  // ---- 1. split fp32 -> bf16 hi/lo ----
  const int NX = 8192*512, NW = 512*512;
  split_kernel<<<2048, 256, 0, stream>>>(query, xq_hi, xq_lo, NX);
  split_kernel<<<2048, 256, 0, stream>>>(mod1,  x1_hi, x1_lo, NX);
  split_kernel<<<2048, 256, 0, stream>>>(mod2,  x2_hi, x2_lo, NX);
  for (int i = 0; i < 8; ++i)
    split_kernel<<<512, 256, 0, stream>>>((const float*)d_in[widx[i]], w_hi[i], w_lo[i], NW);

  // ---- 2. projections ----
  dim3 gg(128, 8);
  gemm_split_kernel<3,1><<<gg, 256, 0, stream>>>(xq_hi, xq_lo, w_hi[0], w_lo[0],
      bq, 0.125f, nullptr, qh_hi, qh_lo);                         // q (scaled)
  gemm_split_kernel<3,1><<<gg, 256, 0, stream>>>(x1_hi, x1_lo, w_hi[1], w_lo[1],
      bk1, 1.0f, nullptr, k1h_hi, k1h_lo);                        // k1
  gemm_split_kernel<3,1><<<gg, 256, 0, stream>>>(x2_hi, x2_lo, w_hi[2], w_lo[2],
      bk2, 1.0f, nullptr, k2h_hi, k2h_lo);                        // k2
  gemm_split_kernel<3,0><<<gg, 256, 0, stream>>>(x1_hi, x1_lo, w_hi[3], w_lo[3],
      bv1, 1.0f, v1b, nullptr, nullptr);                          // v1
  gemm_split_kernel<1,0><<<gg, 256, 0, stream>>>(x1_hi, nullptr, w_hi[5], nullptr,
      bg1, 1.0f, g1b, nullptr, nullptr);                          // g1 (bf16 ok)
  gemm_split_kernel<3,0><<<gg, 256, 0, stream>>>(x2_hi, x2_lo, w_hi[4], w_lo[4],
      bv2, 1.0f, v2b, nullptr, nullptr);                          // v2
  gemm_split_kernel<1,0><<<gg, 256, 0, stream>>>(x2_hi, nullptr, w_hi[6], nullptr,
      bg2, 1.0f, g2b, nullptr, nullptr);                          // g2

  // ---- 3. gram scalars + gated V (transposed split) ----
  norms_kernel<<<256, 256, 0, stream>>>(qh_hi, qh_lo, k1h_hi, k1h_lo,
                                        k2h_hi, k2h_lo, llv, vvv, aav, vav);
  gate_kernel<<<dim3(16, 64), 256, 0, stream>>>(v1b, g1b, v2b, g2b, vT_hi, vT_lo);

  // ---- 4. fused gram-det attention ----
  attn_kernel<<<dim3(16, 64), 256, 0, stream>>>(
      qh_hi, qh_lo, k1h_hi, k1h_lo, k2h_hi, k2h_lo, vT_hi, vT_lo,
      llv, vvv, aav, vav, ao_hi, ao_lo);

  // ---- 5. output projection -> d_out (fp32) ----
  gemm_split_kernel<3,0><<<gg, 256, 0, stream>>>(ao_hi, ao_lo, w_hi[7], w_lo[7],
      bo, 1.0f, (float*)d_out, nullptr, nullptr);
}

// Round 2
// 493.415 us; speedup vs baseline: 1.1761x; 1.1761x over previous
//
#include <hip/hip_runtime.h>
#include <math.h>

// ============================================================================
// TransformerEncoder_gram round 2:
//  - 128x128 double-buffered global_load_lds GEMMs (split-bf16 3-pass)
//  - fused v*sigmoid(g) gate epilogue (saves 2 GEMMs + gate kernel + 128MB)
//  - attn: P single-bf16 (PV 2-pass), cvt_pk packing, defer-max THR=8
// ============================================================================

typedef short bf16x8 __attribute__((ext_vector_type(8)));
typedef float f32x4  __attribute__((ext_vector_type(4)));

#define MFMA16(a,b,c) __builtin_amdgcn_mfma_f32_16x16x32_bf16((a),(b),(c),0,0,0)

static constexpr float LOG2E_F = 1.4426950408889634f;

typedef const __attribute__((address_space(1))) unsigned int gas_u32;
typedef __attribute__((address_space(3))) unsigned int las_u32;

__device__ __forceinline__ void gload16(const void* g, void* l){
  __builtin_amdgcn_global_load_lds((gas_u32*)g, (las_u32*)l, 16, 0, 0);
}

__device__ __forceinline__ float b2f(unsigned short s){
  union { unsigned u; float f; } v; v.u = ((unsigned)s) << 16; return v.f;
}
__device__ __forceinline__ unsigned short f2b(float f){
  union { float f; unsigned u; } v; v.f = f;
  unsigned r = v.u + 0x7fffu + ((v.u >> 16) & 1u);
  return (unsigned short)(r >> 16);
}

// ---------------------------------------------------------------------------
// split fp32 -> (hi, lo) bf16 pair; 3 tensors in one launch (blockIdx.y).
// ---------------------------------------------------------------------------
__global__ __launch_bounds__(256) void split3_kernel(
    const float* __restrict__ a, const float* __restrict__ b,
    const float* __restrict__ c,
    unsigned short* __restrict__ hi, unsigned short* __restrict__ lo, int n)
{
  const int y = blockIdx.y;
  const float* src = (y == 0) ? a : ((y == 1) ? b : c);
  unsigned short* h = hi + (size_t)y * n;
  unsigned short* L = lo + (size_t)y * n;
  int stride = gridDim.x * 256;
  for (int i = blockIdx.x*256 + threadIdx.x; i < n; i += stride){
    float v = src[i];
    unsigned short hh = f2b(v);
    h[i] = hh;
    L[i] = f2b(v - b2f(hh));
  }
}

__global__ __launch_bounds__(256) void splitW_kernel(
    const float* w0, const float* w1, const float* w2, const float* w3,
    const float* w4, const float* w5, const float* w6, const float* w7,
    unsigned short* __restrict__ hi, unsigned short* __restrict__ lo, int n)
{
  const int y = blockIdx.y;
  const float* src = w0;
  if (y == 1) src = w1; if (y == 2) src = w2; if (y == 3) src = w3;
  if (y == 4) src = w4; if (y == 5) src = w5; if (y == 6) src = w6;
  if (y == 7) src = w7;
  unsigned short* h = hi + (size_t)y * n;
  unsigned short* L = lo + (size_t)y * n;
  int stride = gridDim.x * 256;
  for (int i = blockIdx.x*256 + threadIdx.x; i < n; i += stride){
    float v = src[i];
    unsigned short hh = f2b(v);
    h[i] = hh;
    L[i] = f2b(v - b2f(hh));
  }
}

// ---------------------------------------------------------------------------
// 128x128 split-bf16 GEMM, BK=32, double-buffered global_load_lds (16B).
// C(r,e) = sum_k A(r,k)*B(e,k); A: [8192][512], B: [512][512] (both K-contig).
// 3-pass: AhiBhi + AhiBlo + AloBhi.  Pre-swizzled source granule
// g' = g ^ ((row>>1)&3) so LDS stays linear (global_load_lds constraint) and
// frag ds_read_b128 lands at 2-way bank aliasing (free).
// EPI: 0=fp32 (bias,scale); 1=head-split bf16 hi/lo; 2=gate v*sigmoid(g).
// ---------------------------------------------------------------------------
enum { EPI_F32 = 0, EPI_HEADS = 1, EPI_GATE = 2 };

template<int EPI, bool ACCUM>
__global__ __launch_bounds__(256,1) void gemm128_kernel(
    const unsigned short* __restrict__ Ahi, const unsigned short* __restrict__ Alo,
    const unsigned short* __restrict__ Bhi, const unsigned short* __restrict__ Blo,
    const unsigned short* __restrict__ Bg,
    const float* __restrict__ bias, const float* __restrict__ biasg,
    float scale,
    float* __restrict__ outF,
    unsigned short* __restrict__ outHi, unsigned short* __restrict__ outLo)
{
  constexpr int NARR = (EPI == EPI_GATE) ? 5 : 4;
  __shared__ unsigned short smem[2*NARR*4096];

  const int tid = threadIdx.x, w = tid >> 6, l = tid & 63;
  const int r0 = blockIdx.x * 128, e0 = blockIdx.y * 128;
  const int lrow = l & 15, kg = l >> 4;

  f32x4 acc[4][4];
  #pragma unroll
  for (int m = 0; m < 4; ++m)
    #pragma unroll
    for (int n = 0; n < 4; ++n) acc[m][n] = (f32x4){0.f,0.f,0.f,0.f};
  f32x4 gacc[4][4];
  if constexpr (EPI == EPI_GATE){
    #pragma unroll
    for (int m = 0; m < 4; ++m)
      #pragma unroll
      for (int n = 0; n < 4; ++n) gacc[m][n] = (f32x4){0.f,0.f,0.f,0.f};
  }

  // staging addresses: wave w stages rows [w*16+j*64, +16), lane -> (row=l>>2, g=l&3)
  const int sgsw = ((l & 3) ^ ((l >> 3) & 3)) * 8;        // swizzled granule (elems)
  const int srA = r0 + w*16 + (l >> 2);
  const int srB = e0 + w*16 + (l >> 2);

  auto stage = [&](int buf, int kk){
    const int lb = buf*NARR*4096 + w*512;
    #pragma unroll
    for (int j = 0; j < 2; ++j){
      const size_t ga = (size_t)(srA + j*64)*512 + kk + sgsw;
      const size_t gb = (size_t)(srB + j*64)*512 + kk + sgsw;
      gload16(&Ahi[ga], &smem[lb + 0*4096 + j*2048]);
      gload16(&Alo[ga], &smem[lb + 1*4096 + j*2048]);
      gload16(&Bhi[gb], &smem[lb + 2*4096 + j*2048]);
      gload16(&Blo[gb], &smem[lb + 3*4096 + j*2048]);
      if constexpr (EPI == EPI_GATE)
        gload16(&Bg[gb], &smem[lb + 4*4096 + j*2048]);
    }
  };

  // fragment read geometry
  const int rowA = (w >> 1)*64 + lrow;
  const int rowB = (w & 1)*64 + lrow;
  const int kgs  = (kg ^ ((lrow >> 1) & 3)) * 8;

  auto compute = [&](int buf){
    const int bb = buf*NARR*4096;
    bf16x8 ah[4], al[4];
    #pragma unroll
    for (int m = 0; m < 4; ++m){
      const int ra = (rowA + m*16)*32 + kgs;
      ah[m] = *(const bf16x8*)&smem[bb + ra];
      al[m] = *(const bf16x8*)&smem[bb + 4096 + ra];
    }
    #pragma unroll
    for (int n = 0; n < 4; ++n){
      const int rb = (rowB + n*16)*32 + kgs;
      bf16x8 bh = *(const bf16x8*)&smem[bb + 8192 + rb];
      bf16x8 bl = *(const bf16x8*)&smem[bb + 12288 + rb];
      #pragma unroll
      for (int m = 0; m < 4; ++m){
        acc[m][n] = MFMA16(ah[m], bh, acc[m][n]);
        acc[m][n] = MFMA16(ah[m], bl, acc[m][n]);
        acc[m][n] = MFMA16(al[m], bh, acc[m][n]);
      }
      if constexpr (EPI == EPI_GATE){
        bf16x8 bg = *(const bf16x8*)&smem[bb + 16384 + rb];
        #pragma unroll
        for (int m = 0; m < 4; ++m)
          gacc[m][n] = MFMA16(ah[m], bg, gacc[m][n]);
      }
    }
  };

  stage(0, 0);
  __syncthreads();                    // drains vmcnt(0): buf0 ready
  for (int t = 0; t < 16; ++t){
    if (t < 15) stage((t+1) & 1, (t+1)*32);   // overlap with compute
    compute(t & 1);
    __syncthreads();                  // drains stage loads + barrier
  }

  // ---- epilogue ----
  #pragma unroll
  for (int n = 0; n < 4; ++n){
    const int e = e0 + (w & 1)*64 + n*16 + lrow;
    const float bv = bias[e];
    float bgv;
    if constexpr (EPI == EPI_GATE) bgv = biasg[e];
    #pragma unroll
    for (int m = 0; m < 4; ++m){
      #pragma unroll
      for (int q = 0; q < 4; ++q){
        const int r = r0 + (w >> 1)*64 + m*16 + kg*4 + q;
        if constexpr (EPI == EPI_F32){
          outF[(size_t)r*512 + e] = (acc[m][n][q] + bv) * scale;
        } else if constexpr (EPI == EPI_HEADS){
          const float y = (acc[m][n][q] + bv) * scale;
          const int bh = ((r & 7) << 3) + (e >> 6);
          const size_t off = ((size_t)bh*1024 + (r >> 3))*64 + (e & 63);
          unsigned short hh = f2b(y);
          outHi[off] = hh;
          outLo[off] = f2b(y - b2f(hh));
        } else {
          const float yv = acc[m][n][q] + bv;
          const float yg = gacc[m][n][q] + bgv;
          const float sg = 1.0f / (1.0f + exp2f(-yg * LOG2E_F));
          float o = yv * sg;
          if constexpr (ACCUM) o += outF[(size_t)r*512 + e];
          outF[(size_t)r*512 + e] = o;
        }
      }
    }
  }
}

// ---------------------------------------------------------------------------
// Per-(bh,t) gram scalars: ll=|q|^2, vv=|k1|^2, aa=|k2|^2, va=k1.k2  (fp32)
// ---------------------------------------------------------------------------
__global__ __launch_bounds__(256) void norms_kernel(
    const unsigned short* __restrict__ qh, const unsigned short* __restrict__ ql,
    const unsigned short* __restrict__ k1h, const unsigned short* __restrict__ k1l,
    const unsigned short* __restrict__ k2h, const unsigned short* __restrict__ k2l,
    float* __restrict__ ll, float* __restrict__ vv,
    float* __restrict__ aa, float* __restrict__ va)
{
  const int idx = blockIdx.x*256 + threadIdx.x;
  const size_t base = (size_t)idx * 64;
  float sll = 0.f, svv = 0.f, saa = 0.f, sva = 0.f;
  #pragma unroll
  for (int j = 0; j < 8; ++j){
    bf16x8 q_h = *(const bf16x8*)&qh[base + j*8];
    bf16x8 q_l = *(const bf16x8*)&ql[base + j*8];
    bf16x8 a_h = *(const bf16x8*)&k1h[base + j*8];
    bf16x8 a_l = *(const bf16x8*)&k1l[base + j*8];
    bf16x8 c_h = *(const bf16x8*)&k2h[base + j*8];
    bf16x8 c_l = *(const bf16x8*)&k2l[base + j*8];
    #pragma unroll
    for (int i = 0; i < 8; ++i){
      float qv = b2f((unsigned short)q_h[i]) + b2f((unsigned short)q_l[i]);
      float a1 = b2f((unsigned short)a_h[i]) + b2f((unsigned short)a_l[i]);
      float a2 = b2f((unsigned short)c_h[i]) + b2f((unsigned short)c_l[i]);
      sll += qv*qv; svv += a1*a1; saa += a2*a2; sva += a1*a2;
    }
  }
  ll[idx] = sll; vv[idx] = svv; aa[idx] = saa; va[idx] = sva;
}

// ---------------------------------------------------------------------------
// gated-v fp32 [r][e]  ->  transposed split bf16 vT[bh][d][s]
// ---------------------------------------------------------------------------
__global__ __launch_bounds__(256) void vtrans_kernel(
    const float* __restrict__ v,
    unsigned short* __restrict__ vTh, unsigned short* __restrict__ vTl)
{
  __shared__ unsigned short sH[64*64];
  __shared__ unsigned short sL[64*64];
  const int bh = blockIdx.y, b = bh >> 3, h = bh & 7;
  const int s0 = blockIdx.x * 64;
  const int tid = threadIdx.x;
  for (int c = tid; c < 1024; c += 256){
    const int i = c >> 4, sl = c & 15;
    const size_t g = ((size_t)(s0 + i)*8 + b)*512 + h*64 + sl*4;
    f32x4 a = *(const f32x4*)&v[g];
    #pragma unroll
    for (int e = 0; e < 4; ++e){
      const float val = a[e];
      const int d = sl*4 + e;
      unsigned short hh = f2b(val);
      sH[d*64 + i] = hh;
      sL[d*64 + i] = f2b(val - b2f(hh));
    }
  }
  __syncthreads();
  for (int c = tid; c < 512; c += 256){
    const int d = c >> 3, sl = c & 7;
    const size_t g = ((size_t)bh*64 + d)*1024 + s0 + sl*8;
    *(bf16x8*)&vTh[g] = *(const bf16x8*)&sH[d*64 + sl*8];
    *(bf16x8*)&vTl[g] = *(const bf16x8*)&sL[d*64 + sl*8];
  }
}

// ---------------------------------------------------------------------------
// Fused gram-det attention, flash-style online softmax with defer-max.
// QK^T split-bf16 3-pass; P single bf16 (cvt_pk); PV 2-pass (V split).
// ---------------------------------------------------------------------------
__global__ __launch_bounds__(256) void attn_kernel(
    const unsigned short* __restrict__ qhh, const unsigned short* __restrict__ qhl,
    const unsigned short* __restrict__ k1hh, const unsigned short* __restrict__ k1hl,
    const unsigned short* __restrict__ k2hh, const unsigned short* __restrict__ k2hl,
    const unsigned short* __restrict__ vTh, const unsigned short* __restrict__ vTl,
    const float* __restrict__ llv, const float* __restrict__ vvv,
    const float* __restrict__ aav, const float* __restrict__ vav,
    unsigned short* __restrict__ aoHi, unsigned short* __restrict__ aoLo)
{
  __shared__ unsigned short sK1h[64*64];
  __shared__ unsigned short sK1l[64*64];
  __shared__ unsigned short sK2h[64*64];
  __shared__ unsigned short sK2l[64*64];
  __shared__ unsigned short sVh[64*64];
  __shared__ unsigned short sVl[64*64];
  __shared__ unsigned short sPh[4*16*64];
  __shared__ float sNrm[3][64];

  const int bh = blockIdx.y, l0 = blockIdx.x * 64;
  const int tid = threadIdx.x, w = tid >> 6, lane = tid & 63;
  const int lrow = lane & 15, kg = lane >> 4;

  bf16x8 qfh[2], qfl[2];
  {
    const size_t qb = ((size_t)bh*1024 + l0 + w*16 + lrow)*64 + kg*8;
    qfh[0] = *(const bf16x8*)&qhh[qb];
    qfl[0] = *(const bf16x8*)&qhl[qb];
    qfh[1] = *(const bf16x8*)&qhh[qb + 32];
    qfl[1] = *(const bf16x8*)&qhl[qb + 32];
  }
  float ll_r[4];
  #pragma unroll
  for (int q = 0; q < 4; ++q)
    ll_r[q] = llv[bh*1024 + l0 + w*16 + kg*4 + q];

  f32x4 accO[4];
  #pragma unroll
  for (int i = 0; i < 4; ++i) accO[i] = (f32x4){0.f,0.f,0.f,0.f};
  float m_run[4], s_run[4];
  #pragma unroll
  for (int q = 0; q < 4; ++q){ m_run[q] = -__builtin_inff(); s_run[q] = 0.f; }

  for (int ss = 0; ss < 1024; ss += 64){
    // ---- stage K1/K2/VT tiles (XOR-swizzled 16B slots) + norm slices ----
    for (int c = tid; c < 512; c += 256){
      const int r = c >> 3, sl = c & 7;
      const int la = r*64 + ((sl ^ (r & 7)) * 8);
      const size_t gk = ((size_t)bh*1024 + ss + r)*64 + sl*8;
      *(bf16x8*)&sK1h[la] = *(const bf16x8*)&k1hh[gk];
      *(bf16x8*)&sK1l[la] = *(const bf16x8*)&k1hl[gk];
      *(bf16x8*)&sK2h[la] = *(const bf16x8*)&k2hh[gk];
      *(bf16x8*)&sK2l[la] = *(const bf16x8*)&k2hl[gk];
      const size_t gv = ((size_t)bh*64 + r)*1024 + ss + sl*8;
      *(bf16x8*)&sVh[la] = *(const bf16x8*)&vTh[gv];
      *(bf16x8*)&sVl[la] = *(const bf16x8*)&vTl[gv];
    }
    if (tid < 192){
      const int which = tid >> 6, t_ = tid & 63;
      const float* src = (which == 0) ? vvv : ((which == 1) ? aav : vav);
      sNrm[which][t_] = src[bh*1024 + ss + t_];
    }
    __syncthreads();

    // ---- QK^T: lv = q.k1, la = q.k2 (split-bf16, 3 products each) ----
    f32x4 lv[4], la2[4];
    #pragma unroll
    for (int i = 0; i < 4; ++i){ lv[i] = (f32x4){0.f,0.f,0.f,0.f}; la2[i] = (f32x4){0.f,0.f,0.f,0.f}; }
    #pragma unroll
    for (int nt = 0; nt < 4; ++nt){
      #pragma unroll
      for (int ks = 0; ks < 2; ++ks){
        const int row = nt*16 + lrow;
        const int off = row*64 + (((ks*4 + kg) ^ (row & 7)) * 8);
        bf16x8 b1h = *(const bf16x8*)&sK1h[off];
        bf16x8 b1l = *(const bf16x8*)&sK1l[off];
        bf16x8 b2h = *(const bf16x8*)&sK2h[off];
        bf16x8 b2l = *(const bf16x8*)&sK2l[off];
        lv[nt]  = MFMA16(qfh[ks], b1h, lv[nt]);
        lv[nt]  = MFMA16(qfh[ks], b1l, lv[nt]);
        lv[nt]  = MFMA16(qfl[ks], b1h, lv[nt]);
        la2[nt] = MFMA16(qfh[ks], b2h, la2[nt]);
        la2[nt] = MFMA16(qfh[ks], b2l, la2[nt]);
        la2[nt] = MFMA16(qfl[ks], b2h, la2[nt]);
      }
    }

    // ---- gram det -> score ----
    float p_[4][4];
    float tm[4];
    #pragma unroll
    for (int q = 0; q < 4; ++q) tm[q] = -__builtin_inff();
    #pragma unroll
    for (int nt = 0; nt < 4; ++nt){
      const int scol = nt*16 + lrow;
      const float c_vv = sNrm[0][scol], c_aa = sNrm[1][scol], c_va = sNrm[2][scol];
      const float cross = c_vv*c_aa - c_va*c_va;
      #pragma unroll
      for (int q = 0; q < 4; ++q){
        const float flv = lv[nt][q], fla = la2[nt][q];
        float det = ll_r[q]*cross - flv*(flv*c_aa - fla*c_va)
                                  + fla*(flv*c_va - fla*c_vv);
        float sc = -sqrtf(fmaxf(det, 1e-8f));
        p_[nt][q] = sc;
        tm[q] = fmaxf(tm[q], sc);
      }
    }
    #pragma unroll
    for (int q = 0; q < 4; ++q){
      tm[q] = fmaxf(tm[q], __shfl_xor(tm[q], 1));
      tm[q] = fmaxf(tm[q], __shfl_xor(tm[q], 2));
      tm[q] = fmaxf(tm[q], __shfl_xor(tm[q], 4));
      tm[q] = fmaxf(tm[q], __shfl_xor(tm[q], 8));
    }
    // ---- defer-max (T13, THR=8): rescale only when max grows past THR ----
    int up = 0;
    #pragma unroll
    for (int q = 0; q < 4; ++q) up |= (tm[q] > m_run[q] + 8.0f) ? 1 : 0;
    if (__any(up)){
      #pragma unroll
      for (int q = 0; q < 4; ++q){
        const float mn = fmaxf(m_run[q], tm[q]);
        const float rs = exp2f((m_run[q] - mn) * LOG2E_F);
        m_run[q] = mn;
        s_run[q] *= rs;
        #pragma unroll
        for (int dt = 0; dt < 4; ++dt) accO[dt][q] *= rs;
      }
    }
    float psum[4];
    #pragma unroll
    for (int q = 0; q < 4; ++q) psum[q] = 0.f;
    #pragma unroll
    for (int nt = 0; nt < 4; ++nt){
      #pragma unroll
      for (int q = 0; q < 4; ++q){
        const float e = exp2f((p_[nt][q] - m_run[q]) * LOG2E_F);
        p_[nt][q] = e;
        psum[q] += e;
      }
    }
    #pragma unroll
    for (int q = 0; q < 4; ++q){
      psum[q] += __shfl_xor(psum[q], 1);
      psum[q] += __shfl_xor(psum[q], 2);
      psum[q] += __shfl_xor(psum[q], 4);
      psum[q] += __shfl_xor(psum[q], 8);
      s_run[q] += psum[q];
    }

    // ---- P -> LDS, single bf16 via v_cvt_pk_bf16_f32 pairs (rows q,q+1) ----
    #pragma unroll
    for (int nt = 0; nt < 4; ++nt){
      const int col = nt*16 + lrow;
      #pragma unroll
      for (int qp = 0; qp < 2; ++qp){
        unsigned int pk;
        asm("v_cvt_pk_bf16_f32 %0, %1, %2" : "=v"(pk)
            : "v"(p_[nt][qp*2]), "v"(p_[nt][qp*2+1]));
        const int ra = kg*4 + qp*2, rb = ra + 1;
        const int offa = w*1024 + ra*64 + (((col >> 3) ^ (ra & 7))*8) + (col & 7);
        const int offb = w*1024 + rb*64 + (((col >> 3) ^ (rb & 7))*8) + (col & 7);
        sPh[offa] = (unsigned short)(pk & 0xffffu);
        sPh[offb] = (unsigned short)(pk >> 16);
      }
    }

    // ---- PV: accO += P * (Vhi + Vlo)  (2-pass) ----
    #pragma unroll
    for (int ks = 0; ks < 2; ++ks){
      const int poff = w*1024 + lrow*64 + (((ks*4 + kg) ^ (lrow & 7)) * 8);
      bf16x8 pah = *(const bf16x8*)&sPh[poff];
      #pragma unroll
      for (int dt = 0; dt < 4; ++dt){
        const int vrow = dt*16 + lrow;
        const int voff = vrow*64 + (((ks*4 + kg) ^ (vrow & 7)) * 8);
        bf16x8 bvh = *(const bf16x8*)&sVh[voff];
        bf16x8 bvl = *(const bf16x8*)&sVl[voff];
        accO[dt] = MFMA16(pah, bvh, accO[dt]);
        accO[dt] = MFMA16(pah, bvl, accO[dt]);
      }
    }
    __syncthreads();
  }

  // ---- normalize + write attn-out as split bf16 [r=(l*8+b)][e=h*64+d] ----
  const int b = bh >> 3, h = bh & 7;
  #pragma unroll
  for (int dt = 0; dt < 4; ++dt){
    const int d = dt*16 + lrow;
    #pragma unroll
    for (int q = 0; q < 4; ++q){
      const int l_ = l0 + w*16 + kg*4 + q;
      const float o = accO[dt][q] / s_run[q];
      const size_t off = ((size_t)l_*8 + b)*512 + h*64 + d;
      unsigned short hh = f2b(o);
      aoHi[off] = hh;
      aoLo[off] = f2b(o - b2f(hh));
    }
  }
}

// ===========================================================================
extern "C" void kernel_launch(void* const* d_in, const int* in_sizes, int n_in,
                              void* d_out, int out_size, void* d_ws, size_t ws_size,
                              hipStream_t stream)
{
  const float* query = (const float*)d_in[0];
  const float* mod1  = (const float*)d_in[1];
  const float* mod2  = (const float*)d_in[2];
  const float* bq  = (const float*)d_in[4];
  const float* bk1 = (const float*)d_in[6];
  const float* bk2 = (const float*)d_in[8];
  const float* bv1 = (const float*)d_in[10];
  const float* bv2 = (const float*)d_in[12];
  const float* bg1 = (const float*)d_in[14];
  const float* bg2 = (const float*)d_in[16];
  const float* bo  = (const float*)d_in[18];

  char* p = (char*)d_ws;
  auto take = [&](size_t bytes) -> char* {
    char* r = p; p += (bytes + 255) & ~(size_t)255; return r;
  };
  const size_t NX = (size_t)8192*512;     // input elems
  const size_t NW = (size_t)512*512;      // weight elems
  const size_t XB = NX*2, WB = NW*2;
  const size_t HB = (size_t)64*1024*64*2; // bf16 head-layout buffer
  const size_t FB = NX*4;                 // fp32 intermediate
  const size_t NB = (size_t)64*1024*4;

  unsigned short* xhi = (unsigned short*)take(3*XB);   // q, mod1, mod2
  unsigned short* xlo = (unsigned short*)take(3*XB);
  unsigned short* whi = (unsigned short*)take(8*WB);   // Wq,Wk1,Wk2,Wv1,Wv2,Wg1,Wg2,Wo
  unsigned short* wlo = (unsigned short*)take(8*WB);
  unsigned short* qh_hi  = (unsigned short*)take(HB);
  unsigned short* qh_lo  = (unsigned short*)take(HB);
  unsigned short* k1h_hi = (unsigned short*)take(HB);
  unsigned short* k1h_lo = (unsigned short*)take(HB);
  unsigned short* k2h_hi = (unsigned short*)take(HB);
  unsigned short* k2h_lo = (unsigned short*)take(HB);
  unsigned short* vT_hi  = (unsigned short*)take(HB);
  unsigned short* vT_lo  = (unsigned short*)take(HB);
  float* vacc = (float*)take(FB);
  unsigned short* ao_hi = (unsigned short*)take(HB);
  unsigned short* ao_lo = (unsigned short*)take(HB);
  float* llv = (float*)take(NB);
  float* vvv = (float*)take(NB);
  float* aav = (float*)take(NB);
  float* vav = (float*)take(NB);

  unsigned short* xq_hi = xhi;            unsigned short* xq_lo = xlo;
  unsigned short* x1_hi = xhi + NX;       unsigned short* x1_lo = xlo + NX;
  unsigned short* x2_hi = xhi + 2*NX;     unsigned short* x2_lo = xlo + 2*NX;

  // ---- 1. splits ----
  split3_kernel<<<dim3(1024,3), 256, 0, stream>>>(query, mod1, mod2, xhi, xlo, (int)NX);
  splitW_kernel<<<dim3(256,8), 256, 0, stream>>>(
      (const float*)d_in[3], (const float*)d_in[5], (const float*)d_in[7],
      (const float*)d_in[9], (const float*)d_in[11], (const float*)d_in[13],
      (const float*)d_in[15], (const float*)d_in[17], whi, wlo, (int)NW);

  // ---- 2. projections (128x128 tiles, 64x4 = 256 blocks) ----
  dim3 gg(64, 4);
  gemm128_kernel<EPI_HEADS,false><<<gg, 256, 0, stream>>>(
      xq_hi, xq_lo, whi + 0*NW, wlo + 0*NW, nullptr, bq, nullptr, 0.125f,
      nullptr, qh_hi, qh_lo);
  gemm128_kernel<EPI_HEADS,false><<<gg, 256, 0, stream>>>(
      x1_hi, x1_lo, whi + 1*NW, wlo + 1*NW, nullptr, bk1, nullptr, 1.0f,
      nullptr, k1h_hi, k1h_lo);
  gemm128_kernel<EPI_HEADS,false><<<gg, 256, 0, stream>>>(
      x2_hi, x2_lo, whi + 2*NW, wlo + 2*NW, nullptr, bk2, nullptr, 1.0f,
      nullptr, k2h_hi, k2h_lo);
  gemm128_kernel<EPI_GATE,false><<<gg, 256, 0, stream>>>(
      x1_hi, x1_lo, whi + 3*NW, wlo + 3*NW, whi + 5*NW, bv1, bg1, 1.0f,
      vacc, nullptr, nullptr);
  gemm128_kernel<EPI_GATE,true><<<gg, 256, 0, stream>>>(
      x2_hi, x2_lo, whi + 4*NW, wlo + 4*NW, whi + 6*NW, bv2, bg2, 1.0f,
      vacc, nullptr, nullptr);

  // ---- 3. gram scalars + gated-V transpose ----
  norms_kernel<<<256, 256, 0, stream>>>(qh_hi, qh_lo, k1h_hi, k1h_lo,
                                        k2h_hi, k2h_lo, llv, vvv, aav, vav);
  vtrans_kernel<<<dim3(16, 64), 256, 0, stream>>>(vacc, vT_hi, vT_lo);

  // ---- 4. fused gram-det attention ----
  attn_kernel<<<dim3(16, 64), 256, 0, stream>>>(
      qh_hi, qh_lo, k1h_hi, k1h_lo, k2h_hi, k2h_lo, vT_hi, vT_lo,
      llv, vvv, aav, vav, ao_hi, ao_lo);

  // ---- 5. output projection -> d_out (fp32) ----
  gemm128_kernel<EPI_F32,false><<<gg, 256, 0, stream>>>(
      ao_hi, ao_lo, whi + 7*NW, wlo + 7*NW, nullptr, bo, nullptr, 1.0f,
      (float*)d_out, nullptr, nullptr);
}

// Round 4
// 418.438 us; speedup vs baseline: 1.3868x; 1.1792x over previous
//
#include <hip/hip_runtime.h>
#include <math.h>

// ============================================================================
// TransformerEncoder_gram round 3 (resubmit — R3 bench was GPU-acquisition
// timeout, no data):
//  - attn QBLK=128 (4 waves x 32 rows): halves staging + K-read cost per row
//  - attn staging via global_load_lds w/ swizzled per-lane SOURCE addresses
//  - V single-bf16 (PV 1-pass), ao single-bf16 (final GEMM 2-pass)
//  - packed norms float4 {cross, aa, 2va, vv}; log2e folded into q/k scaling
// ============================================================================

typedef short bf16x8 __attribute__((ext_vector_type(8)));
typedef float f32x4  __attribute__((ext_vector_type(4)));

#define MFMA16(a,b,c) __builtin_amdgcn_mfma_f32_16x16x32_bf16((a),(b),(c),0,0,0)

static constexpr float LOG2E_F = 1.4426950408889634f;
// log2e^(1/3): folded into q,k1,k2 so -sqrt(det) is already in log2 units
static constexpr float CBRT_L2E = 1.12994722f;
static constexpr float DEFER_THR = 11.54156033f;   // 8 * log2e
static constexpr float EPS_SCALED = 2.0813689e-8f; // 1e-8 * log2e^2

typedef const __attribute__((address_space(1))) unsigned int gas_u32;
typedef __attribute__((address_space(3))) unsigned int las_u32;

__device__ __forceinline__ void gload16(const void* g, void* l){
  __builtin_amdgcn_global_load_lds((gas_u32*)g, (las_u32*)l, 16, 0, 0);
}

__device__ __forceinline__ float b2f(unsigned short s){
  union { unsigned u; float f; } v; v.u = ((unsigned)s) << 16; return v.f;
}
__device__ __forceinline__ unsigned short f2b(float f){
  union { float f; unsigned u; } v; v.f = f;
  unsigned r = v.u + 0x7fffu + ((v.u >> 16) & 1u);
  return (unsigned short)(r >> 16);
}

// ---------------------------------------------------------------------------
// split fp32 -> (hi, lo) bf16 pair; 3 tensors in one launch (blockIdx.y).
// ---------------------------------------------------------------------------
__global__ __launch_bounds__(256) void split3_kernel(
    const float* __restrict__ a, const float* __restrict__ b,
    const float* __restrict__ c,
    unsigned short* __restrict__ hi, unsigned short* __restrict__ lo, int n)
{
  const int y = blockIdx.y;
  const float* src = (y == 0) ? a : ((y == 1) ? b : c);
  unsigned short* h = hi + (size_t)y * n;
  unsigned short* L = lo + (size_t)y * n;
  int stride = gridDim.x * 256;
  for (int i = blockIdx.x*256 + threadIdx.x; i < n; i += stride){
    float v = src[i];
    unsigned short hh = f2b(v);
    h[i] = hh;
    L[i] = f2b(v - b2f(hh));
  }
}

__global__ __launch_bounds__(256) void splitW_kernel(
    const float* w0, const float* w1, const float* w2, const float* w3,
    const float* w4, const float* w5, const float* w6, const float* w7,
    unsigned short* __restrict__ hi, unsigned short* __restrict__ lo, int n)
{
  const int y = blockIdx.y;
  const float* src = w0;
  if (y == 1) src = w1; if (y == 2) src = w2; if (y == 3) src = w3;
  if (y == 4) src = w4; if (y == 5) src = w5; if (y == 6) src = w6;
  if (y == 7) src = w7;
  unsigned short* h = hi + (size_t)y * n;
  unsigned short* L = lo + (size_t)y * n;
  int stride = gridDim.x * 256;
  for (int i = blockIdx.x*256 + threadIdx.x; i < n; i += stride){
    float v = src[i];
    unsigned short hh = f2b(v);
    h[i] = hh;
    L[i] = f2b(v - b2f(hh));
  }
}

// ---------------------------------------------------------------------------
// 128x128 split-bf16 GEMM, BK=32, double-buffered global_load_lds (16B).
// NPASS=3: AhiBhi+AhiBlo+AloBhi;  NPASS=2: AhiBhi+AhiBlo (A already bf16).
// EPI: 0=fp32 (bias,scale); 1=head-split bf16 hi/lo; 2=gate v*sigmoid(g).
// ---------------------------------------------------------------------------
enum { EPI_F32 = 0, EPI_HEADS = 1, EPI_GATE = 2 };

template<int NPASS, int EPI, bool ACCUM>
__global__ __launch_bounds__(256,1) void gemm128_kernel(
    const unsigned short* __restrict__ Ahi, const unsigned short* __restrict__ Alo,
    const unsigned short* __restrict__ Bhi, const unsigned short* __restrict__ Blo,
    const unsigned short* __restrict__ Bg,
    const float* __restrict__ bias, const float* __restrict__ biasg,
    float scale,
    float* __restrict__ outF,
    unsigned short* __restrict__ outHi, unsigned short* __restrict__ outLo)
{
  constexpr int iAhi = 0;
  constexpr int iAlo = 1;                         // only when NPASS==3
  constexpr int iBhi = (NPASS == 3) ? 2 : 1;
  constexpr int iBlo = iBhi + 1;
  constexpr int iBg  = iBlo + 1;                  // only for EPI_GATE
  constexpr int NARR = (EPI == EPI_GATE) ? 5 : ((NPASS == 3) ? 4 : 3);
  __shared__ unsigned short smem[2*NARR*4096];

  const int tid = threadIdx.x, w = tid >> 6, l = tid & 63;
  const int r0 = blockIdx.x * 128, e0 = blockIdx.y * 128;
  const int lrow = l & 15, kg = l >> 4;

  f32x4 acc[4][4];
  #pragma unroll
  for (int m = 0; m < 4; ++m)
    #pragma unroll
    for (int n = 0; n < 4; ++n) acc[m][n] = (f32x4){0.f,0.f,0.f,0.f};
  f32x4 gacc[4][4];
  if constexpr (EPI == EPI_GATE){
    #pragma unroll
    for (int m = 0; m < 4; ++m)
      #pragma unroll
      for (int n = 0; n < 4; ++n) gacc[m][n] = (f32x4){0.f,0.f,0.f,0.f};
  }

  const int sgsw = ((l & 3) ^ ((l >> 3) & 3)) * 8;        // swizzled granule
  const int srA = r0 + w*16 + (l >> 2);
  const int srB = e0 + w*16 + (l >> 2);

  auto stage = [&](int buf, int kk){
    const int lb = buf*NARR*4096 + w*512;
    #pragma unroll
    for (int j = 0; j < 2; ++j){
      const size_t ga = (size_t)(srA + j*64)*512 + kk + sgsw;
      const size_t gb = (size_t)(srB + j*64)*512 + kk + sgsw;
      gload16(&Ahi[ga], &smem[lb + iAhi*4096 + j*2048]);
      if constexpr (NPASS == 3)
        gload16(&Alo[ga], &smem[lb + iAlo*4096 + j*2048]);
      gload16(&Bhi[gb], &smem[lb + iBhi*4096 + j*2048]);
      gload16(&Blo[gb], &smem[lb + iBlo*4096 + j*2048]);
      if constexpr (EPI == EPI_GATE)
        gload16(&Bg[gb], &smem[lb + iBg*4096 + j*2048]);
    }
  };

  const int rowA = (w >> 1)*64 + lrow;
  const int rowB = (w & 1)*64 + lrow;
  const int kgs  = (kg ^ ((lrow >> 1) & 3)) * 8;

  auto compute = [&](int buf){
    const int bb = buf*NARR*4096;
    bf16x8 ah[4], al[4];
    #pragma unroll
    for (int m = 0; m < 4; ++m){
      const int ra = (rowA + m*16)*32 + kgs;
      ah[m] = *(const bf16x8*)&smem[bb + iAhi*4096 + ra];
      if constexpr (NPASS == 3)
        al[m] = *(const bf16x8*)&smem[bb + iAlo*4096 + ra];
    }
    #pragma unroll
    for (int n = 0; n < 4; ++n){
      const int rb = (rowB + n*16)*32 + kgs;
      bf16x8 bh = *(const bf16x8*)&smem[bb + iBhi*4096 + rb];
      bf16x8 bl = *(const bf16x8*)&smem[bb + iBlo*4096 + rb];
      #pragma unroll
      for (int m = 0; m < 4; ++m){
        acc[m][n] = MFMA16(ah[m], bh, acc[m][n]);
        acc[m][n] = MFMA16(ah[m], bl, acc[m][n]);
        if constexpr (NPASS == 3)
          acc[m][n] = MFMA16(al[m], bh, acc[m][n]);
      }
      if constexpr (EPI == EPI_GATE){
        bf16x8 bg = *(const bf16x8*)&smem[bb + iBg*4096 + rb];
        #pragma unroll
        for (int m = 0; m < 4; ++m)
          gacc[m][n] = MFMA16(ah[m], bg, gacc[m][n]);
      }
    }
  };

  stage(0, 0);
  __syncthreads();
  for (int t = 0; t < 16; ++t){
    if (t < 15) stage((t+1) & 1, (t+1)*32);
    compute(t & 1);
    __syncthreads();
  }

  #pragma unroll
  for (int n = 0; n < 4; ++n){
    const int e = e0 + (w & 1)*64 + n*16 + lrow;
    const float bv = bias[e];
    float bgv;
    if constexpr (EPI == EPI_GATE) bgv = biasg[e];
    #pragma unroll
    for (int m = 0; m < 4; ++m){
      #pragma unroll
      for (int q = 0; q < 4; ++q){
        const int r = r0 + (w >> 1)*64 + m*16 + kg*4 + q;
        if constexpr (EPI == EPI_F32){
          outF[(size_t)r*512 + e] = (acc[m][n][q] + bv) * scale;
        } else if constexpr (EPI == EPI_HEADS){
          const float y = (acc[m][n][q] + bv) * scale;
          const int bh = ((r & 7) << 3) + (e >> 6);
          const size_t off = ((size_t)bh*1024 + (r >> 3))*64 + (e & 63);
          unsigned short hh = f2b(y);
          outHi[off] = hh;
          outLo[off] = f2b(y - b2f(hh));
        } else {
          const float yv = acc[m][n][q] + bv;
          const float yg = gacc[m][n][q] + bgv;
          const float sg = 1.0f / (1.0f + exp2f(-yg * LOG2E_F));
          float o = yv * sg;
          if constexpr (ACCUM) o += outF[(size_t)r*512 + e];
          outF[(size_t)r*512 + e] = o;
        }
      }
    }
  }
}

// ---------------------------------------------------------------------------
// Per-(bh,t): ll=|q|^2 and packed {cross, aa, 2va, vv} (fp32)
// ---------------------------------------------------------------------------
__global__ __launch_bounds__(256) void norms_kernel(
    const unsigned short* __restrict__ qh, const unsigned short* __restrict__ ql,
    const unsigned short* __restrict__ k1h, const unsigned short* __restrict__ k1l,
    const unsigned short* __restrict__ k2h, const unsigned short* __restrict__ k2l,
    float* __restrict__ ll, f32x4* __restrict__ nrm4)
{
  const int idx = blockIdx.x*256 + threadIdx.x;
  const size_t base = (size_t)idx * 64;
  float sll = 0.f, svv = 0.f, saa = 0.f, sva = 0.f;
  #pragma unroll
  for (int j = 0; j < 8; ++j){
    bf16x8 q_h = *(const bf16x8*)&qh[base + j*8];
    bf16x8 q_l = *(const bf16x8*)&ql[base + j*8];
    bf16x8 a_h = *(const bf16x8*)&k1h[base + j*8];
    bf16x8 a_l = *(const bf16x8*)&k1l[base + j*8];
    bf16x8 c_h = *(const bf16x8*)&k2h[base + j*8];
    bf16x8 c_l = *(const bf16x8*)&k2l[base + j*8];
    #pragma unroll
    for (int i = 0; i < 8; ++i){
      float qv = b2f((unsigned short)q_h[i]) + b2f((unsigned short)q_l[i]);
      float a1 = b2f((unsigned short)a_h[i]) + b2f((unsigned short)a_l[i]);
      float a2 = b2f((unsigned short)c_h[i]) + b2f((unsigned short)c_l[i]);
      sll += qv*qv; svv += a1*a1; saa += a2*a2; sva += a1*a2;
    }
  }
  ll[idx] = sll;
  nrm4[idx] = (f32x4){svv*saa - sva*sva, saa, 2.0f*sva, svv};
}

// ---------------------------------------------------------------------------
// gated-v fp32 [r][e]  ->  transposed bf16 vT[bh][d][s]  (single bf16)
// ---------------------------------------------------------------------------
__global__ __launch_bounds__(256) void vtrans_kernel(
    const float* __restrict__ v, unsigned short* __restrict__ vTh)
{
  __shared__ unsigned short sH[64*64];
  const int bh = blockIdx.y, b = bh >> 3, h = bh & 7;
  const int s0 = blockIdx.x * 64;
  const int tid = threadIdx.x;
  for (int c = tid; c < 1024; c += 256){
    const int i = c >> 4, sl = c & 15;
    const size_t g = ((size_t)(s0 + i)*8 + b)*512 + h*64 + sl*4;
    f32x4 a = *(const f32x4*)&v[g];
    #pragma unroll
    for (int e = 0; e < 4; ++e)
      sH[(sl*4 + e)*64 + i] = f2b(a[e]);
  }
  __syncthreads();
  for (int c = tid; c < 512; c += 256){
    const int d = c >> 3, sl = c & 7;
    const size_t g = ((size_t)bh*64 + d)*1024 + s0 + sl*8;
    *(bf16x8*)&vTh[g] = *(const bf16x8*)&sH[d*64 + sl*8];
  }
}

// ---------------------------------------------------------------------------
// Fused gram-det attention. QBLK=128 (4 waves x 32 rows), KVBLK=64.
// global_load_lds staging (swizzled per-lane source); QK 3-pass split-bf16;
// PV 1-pass; packed norms; scores in log2 units (min-tracked); defer-rescale.
// ---------------------------------------------------------------------------
__global__ __launch_bounds__(256,2) void attn_kernel(
    const unsigned short* __restrict__ qhh, const unsigned short* __restrict__ qhl,
    const unsigned short* __restrict__ k1hh, const unsigned short* __restrict__ k1hl,
    const unsigned short* __restrict__ k2hh, const unsigned short* __restrict__ k2hl,
    const unsigned short* __restrict__ vTh,
    const float* __restrict__ llv, const f32x4* __restrict__ nrm4,
    unsigned short* __restrict__ aoHi)
{
  __shared__ unsigned short sK1h[4096];
  __shared__ unsigned short sK1l[4096];
  __shared__ unsigned short sK2h[4096];
  __shared__ unsigned short sK2l[4096];
  __shared__ unsigned short sVh[4096];
  __shared__ unsigned short sPh[8192];     // 4 waves x 32 x 64
  __shared__ f32x4 sN4[64];

  const int bh = blockIdx.y, l0 = blockIdx.x * 128;
  const int tid = threadIdx.x, w = tid >> 6, lane = tid & 63;
  const int lrow = lane & 15, kg = lane >> 4;

  // Q fragments for both 16-row subtiles, hoisted
  bf16x8 qfh[2][2], qfl[2][2];
  #pragma unroll
  for (int m = 0; m < 2; ++m){
    const size_t qb = ((size_t)bh*1024 + l0 + w*32 + m*16 + lrow)*64 + kg*8;
    qfh[m][0] = *(const bf16x8*)&qhh[qb];
    qfl[m][0] = *(const bf16x8*)&qhl[qb];
    qfh[m][1] = *(const bf16x8*)&qhh[qb + 32];
    qfl[m][1] = *(const bf16x8*)&qhl[qb + 32];
  }
  float ll_r[2][4];
  #pragma unroll
  for (int m = 0; m < 2; ++m)
    #pragma unroll
    for (int q = 0; q < 4; ++q)
      ll_r[m][q] = llv[bh*1024 + l0 + w*32 + m*16 + kg*4 + q];

  f32x4 accO[2][4];
  #pragma unroll
  for (int m = 0; m < 2; ++m)
    #pragma unroll
    for (int i = 0; i < 4; ++i) accO[m][i] = (f32x4){0.f,0.f,0.f,0.f};
  float mn[2][4], s_run[2][4];
  #pragma unroll
  for (int m = 0; m < 2; ++m)
    #pragma unroll
    for (int q = 0; q < 4; ++q){ mn[m][q] = 1e30f; s_run[m][q] = 0.f; }

  // staging geometry: granule c -> LDS c*16B (linear), source granule swizzled
  const int c0 = tid, c1 = tid + 256;
  const int r0g = c0 >> 3, g0 = ((c0 & 7) ^ (r0g & 7)) * 8;
  const int r1g = c1 >> 3, g1 = ((c1 & 7) ^ (r1g & 7)) * 8;

  for (int ss = 0; ss < 1024; ss += 64){
    {
      const size_t kb = (size_t)bh*1024 + ss;
      const size_t k0 = (kb + r0g)*64 + g0;
      const size_t k1_ = (kb + r1g)*64 + g1;
      gload16(&k1hh[k0], &sK1h[c0*8]);  gload16(&k1hh[k1_], &sK1h[c1*8]);
      gload16(&k1hl[k0], &sK1l[c0*8]);  gload16(&k1hl[k1_], &sK1l[c1*8]);
      gload16(&k2hh[k0], &sK2h[c0*8]);  gload16(&k2hh[k1_], &sK2h[c1*8]);
      gload16(&k2hl[k0], &sK2l[c0*8]);  gload16(&k2hl[k1_], &sK2l[c1*8]);
      const size_t v0 = ((size_t)bh*64 + r0g)*1024 + ss + g0;
      const size_t v1 = ((size_t)bh*64 + r1g)*1024 + ss + g1;
      gload16(&vTh[v0], &sVh[c0*8]);    gload16(&vTh[v1], &sVh[c1*8]);
      if (tid < 64) gload16(&nrm4[(size_t)bh*1024 + ss + tid], &sN4[tid]);
    }
    __syncthreads();

    // ---- QK^T + gram det, nt-by-nt (keeps lv/la live range short) ----
    float p_[2][4][4];
    float tmn[2][4];
    #pragma unroll
    for (int m = 0; m < 2; ++m)
      #pragma unroll
      for (int q = 0; q < 4; ++q) tmn[m][q] = 1e30f;

    #pragma unroll
    for (int nt = 0; nt < 4; ++nt){
      f32x4 lv[2], la[2];
      #pragma unroll
      for (int m = 0; m < 2; ++m){ lv[m] = (f32x4){0.f,0.f,0.f,0.f}; la[m] = (f32x4){0.f,0.f,0.f,0.f}; }
      #pragma unroll
      for (int ks = 0; ks < 2; ++ks){
        const int row = nt*16 + lrow;
        const int off = row*64 + (((ks*4 + kg) ^ (row & 7)) * 8);
        bf16x8 b1h = *(const bf16x8*)&sK1h[off];
        bf16x8 b1l = *(const bf16x8*)&sK1l[off];
        bf16x8 b2h = *(const bf16x8*)&sK2h[off];
        bf16x8 b2l = *(const bf16x8*)&sK2l[off];
        #pragma unroll
        for (int m = 0; m < 2; ++m){
          lv[m] = MFMA16(qfh[m][ks], b1h, lv[m]);
          lv[m] = MFMA16(qfh[m][ks], b1l, lv[m]);
          lv[m] = MFMA16(qfl[m][ks], b1h, lv[m]);
          la[m] = MFMA16(qfh[m][ks], b2h, la[m]);
          la[m] = MFMA16(qfh[m][ks], b2l, la[m]);
          la[m] = MFMA16(qfl[m][ks], b2h, la[m]);
        }
      }
      f32x4 n4 = sN4[nt*16 + lrow];
      const float cross = n4[0], c_aa = n4[1], c_va2 = n4[2], c_vv = n4[3];
      #pragma unroll
      for (int m = 0; m < 2; ++m){
        #pragma unroll
        for (int q = 0; q < 4; ++q){
          const float flv = lv[m][q], fla = la[m][q];
          float t = fmaf(-c_vv, fla*fla, (flv*fla)*c_va2);
          t = fmaf(-c_aa, flv*flv, t);
          const float det = fmaf(ll_r[m][q], cross, t);
          const float sq = __builtin_amdgcn_sqrtf(fmaxf(det, EPS_SCALED));
          p_[m][nt][q] = sq;
          tmn[m][q] = fminf(tmn[m][q], sq);
        }
      }
    }
    // min over the 16-lane col group
    #pragma unroll
    for (int m = 0; m < 2; ++m)
      #pragma unroll
      for (int q = 0; q < 4; ++q){
        tmn[m][q] = fminf(tmn[m][q], __shfl_xor(tmn[m][q], 1));
        tmn[m][q] = fminf(tmn[m][q], __shfl_xor(tmn[m][q], 2));
        tmn[m][q] = fminf(tmn[m][q], __shfl_xor(tmn[m][q], 4));
        tmn[m][q] = fminf(tmn[m][q], __shfl_xor(tmn[m][q], 8));
      }
    // defer-rescale (T13)
    int up = 0;
    #pragma unroll
    for (int m = 0; m < 2; ++m)
      #pragma unroll
      for (int q = 0; q < 4; ++q) up |= (tmn[m][q] < mn[m][q] - DEFER_THR) ? 1 : 0;
    if (__any(up)){
      #pragma unroll
      for (int m = 0; m < 2; ++m)
        #pragma unroll
        for (int q = 0; q < 4; ++q){
          const float mnn = fminf(mn[m][q], tmn[m][q]);
          const float rs = __builtin_amdgcn_exp2f(mnn - mn[m][q]);
          mn[m][q] = mnn;
          s_run[m][q] *= rs;
          #pragma unroll
          for (int dt = 0; dt < 4; ++dt) accO[m][dt][q] *= rs;
        }
    }
    // exponentiate (log2 units) + row-sum
    float ps[2][4];
    #pragma unroll
    for (int m = 0; m < 2; ++m)
      #pragma unroll
      for (int q = 0; q < 4; ++q) ps[m][q] = 0.f;
    #pragma unroll
    for (int nt = 0; nt < 4; ++nt)
      #pragma unroll
      for (int m = 0; m < 2; ++m)
        #pragma unroll
        for (int q = 0; q < 4; ++q){
          const float e = __builtin_amdgcn_exp2f(mn[m][q] - p_[m][nt][q]);
          p_[m][nt][q] = e;
          ps[m][q] += e;
        }
    #pragma unroll
    for (int m = 0; m < 2; ++m)
      #pragma unroll
      for (int q = 0; q < 4; ++q){
        float v = ps[m][q];
        v += __shfl_xor(v, 1); v += __shfl_xor(v, 2);
        v += __shfl_xor(v, 4); v += __shfl_xor(v, 8);
        s_run[m][q] += v;
      }

    // ---- P -> LDS (single bf16, cvt_pk pairs over q) ----
    #pragma unroll
    for (int m = 0; m < 2; ++m){
      #pragma unroll
      for (int nt = 0; nt < 4; ++nt){
        const int col = nt*16 + lrow;
        const int cg = col >> 3, cr = col & 7;
        #pragma unroll
        for (int qp = 0; qp < 2; ++qp){
          unsigned int pk;
          asm("v_cvt_pk_bf16_f32 %0, %1, %2" : "=v"(pk)
              : "v"(p_[m][nt][qp*2]), "v"(p_[m][nt][qp*2+1]));
          const int ra = m*16 + kg*4 + qp*2, rb = ra + 1;
          sPh[w*2048 + ra*64 + ((cg ^ (ra & 7))*8) + cr] = (unsigned short)(pk & 0xffffu);
          sPh[w*2048 + rb*64 + ((cg ^ (rb & 7))*8) + cr] = (unsigned short)(pk >> 16);
        }
      }
    }

    // ---- PV: accO += P * Vh (1-pass) ----
    #pragma unroll
    for (int ks = 0; ks < 2; ++ks){
      bf16x8 pa[2];
      #pragma unroll
      for (int m = 0; m < 2; ++m){
        const int prow = m*16 + lrow;
        pa[m] = *(const bf16x8*)&sPh[w*2048 + prow*64 + (((ks*4 + kg) ^ (prow & 7))*8)];
      }
      #pragma unroll
      for (int dt = 0; dt < 4; ++dt){
        const int vrow = dt*16 + lrow;
        bf16x8 bvh = *(const bf16x8*)&sVh[vrow*64 + (((ks*4 + kg) ^ (vrow & 7))*8)];
        #pragma unroll
        for (int m = 0; m < 2; ++m)
          accO[m][dt] = MFMA16(pa[m], bvh, accO[m][dt]);
      }
    }
    __syncthreads();
  }

  // ---- normalize + write attn-out bf16 [r=(l*8+b)][e=h*64+d] ----
  const int b = bh >> 3, h = bh & 7;
  #pragma unroll
  for (int m = 0; m < 2; ++m){
    float rcp[4];
    #pragma unroll
    for (int q = 0; q < 4; ++q) rcp[q] = __builtin_amdgcn_rcpf(s_run[m][q]);
    #pragma unroll
    for (int dt = 0; dt < 4; ++dt){
      const int d = dt*16 + lrow;
      #pragma unroll
      for (int q = 0; q < 4; ++q){
        const int l_ = l0 + w*32 + m*16 + kg*4 + q;
        aoHi[((size_t)l_*8 + b)*512 + h*64 + d] = f2b(accO[m][dt][q] * rcp[q]);
      }
    }
  }
}

// ===========================================================================
extern "C" void kernel_launch(void* const* d_in, const int* in_sizes, int n_in,
                              void* d_out, int out_size, void* d_ws, size_t ws_size,
                              hipStream_t stream)
{
  const float* query = (const float*)d_in[0];
  const float* mod1  = (const float*)d_in[1];
  const float* mod2  = (const float*)d_in[2];
  const float* bq  = (const float*)d_in[4];
  const float* bk1 = (const float*)d_in[6];
  const float* bk2 = (const float*)d_in[8];
  const float* bv1 = (const float*)d_in[10];
  const float* bv2 = (const float*)d_in[12];
  const float* bg1 = (const float*)d_in[14];
  const float* bg2 = (const float*)d_in[16];
  const float* bo  = (const float*)d_in[18];

  char* p = (char*)d_ws;
  auto take = [&](size_t bytes) -> char* {
    char* r = p; p += (bytes + 255) & ~(size_t)255; return r;
  };
  const size_t NX = (size_t)8192*512;
  const size_t NW = (size_t)512*512;
  const size_t XB = NX*2, WB = NW*2;
  const size_t HB = (size_t)64*1024*64*2;
  const size_t FB = NX*4;
  const size_t NB = (size_t)64*1024*4;

  unsigned short* xhi = (unsigned short*)take(3*XB);
  unsigned short* xlo = (unsigned short*)take(3*XB);
  unsigned short* whi = (unsigned short*)take(8*WB);
  unsigned short* wlo = (unsigned short*)take(8*WB);
  unsigned short* qh_hi  = (unsigned short*)take(HB);
  unsigned short* qh_lo  = (unsigned short*)take(HB);
  unsigned short* k1h_hi = (unsigned short*)take(HB);
  unsigned short* k1h_lo = (unsigned short*)take(HB);
  unsigned short* k2h_hi = (unsigned short*)take(HB);
  unsigned short* k2h_lo = (unsigned short*)take(HB);
  unsigned short* vT_hi  = (unsigned short*)take(HB);
  float* vacc = (float*)take(FB);
  unsigned short* ao_hi = (unsigned short*)take(HB);
  float* llv = (float*)take(NB);
  f32x4* nrm4 = (f32x4*)take(4*NB);

  unsigned short* xq_hi = xhi;            unsigned short* xq_lo = xlo;
  unsigned short* x1_hi = xhi + NX;       unsigned short* x1_lo = xlo + NX;
  unsigned short* x2_hi = xhi + 2*NX;     unsigned short* x2_lo = xlo + 2*NX;

  // ---- 1. splits ----
  split3_kernel<<<dim3(1024,3), 256, 0, stream>>>(query, mod1, mod2, xhi, xlo, (int)NX);
  splitW_kernel<<<dim3(256,8), 256, 0, stream>>>(
      (const float*)d_in[3], (const float*)d_in[5], (const float*)d_in[7],
      (const float*)d_in[9], (const float*)d_in[11], (const float*)d_in[13],
      (const float*)d_in[15], (const float*)d_in[17], whi, wlo, (int)NW);

  // ---- 2. projections (log2e^(1/3) folded into q,k1,k2) ----
  dim3 gg(64, 4);
  gemm128_kernel<3,EPI_HEADS,false><<<gg, 256, 0, stream>>>(
      xq_hi, xq_lo, whi + 0*NW, wlo + 0*NW, nullptr, bq, nullptr,
      0.125f*CBRT_L2E, nullptr, qh_hi, qh_lo);
  gemm128_kernel<3,EPI_HEADS,false><<<gg, 256, 0, stream>>>(
      x1_hi, x1_lo, whi + 1*NW, wlo + 1*NW, nullptr, bk1, nullptr,
      CBRT_L2E, nullptr, k1h_hi, k1h_lo);
  gemm128_kernel<3,EPI_HEADS,false><<<gg, 256, 0, stream>>>(
      x2_hi, x2_lo, whi + 2*NW, wlo + 2*NW, nullptr, bk2, nullptr,
      CBRT_L2E, nullptr, k2h_hi, k2h_lo);
  gemm128_kernel<3,EPI_GATE,false><<<gg, 256, 0, stream>>>(
      x1_hi, x1_lo, whi + 3*NW, wlo + 3*NW, whi + 5*NW, bv1, bg1, 1.0f,
      vacc, nullptr, nullptr);
  gemm128_kernel<3,EPI_GATE,true><<<gg, 256, 0, stream>>>(
      x2_hi, x2_lo, whi + 4*NW, wlo + 4*NW, whi + 6*NW, bv2, bg2, 1.0f,
      vacc, nullptr, nullptr);

  // ---- 3. gram scalars + gated-V transpose ----
  norms_kernel<<<256, 256, 0, stream>>>(qh_hi, qh_lo, k1h_hi, k1h_lo,
                                        k2h_hi, k2h_lo, llv, nrm4);
  vtrans_kernel<<<dim3(16, 64), 256, 0, stream>>>(vacc, vT_hi);

  // ---- 4. fused gram-det attention (QBLK=128) ----
  attn_kernel<<<dim3(8, 64), 256, 0, stream>>>(
      qh_hi, qh_lo, k1h_hi, k1h_lo, k2h_hi, k2h_lo, vT_hi,
      llv, nrm4, ao_hi);

  // ---- 5. output projection (2-pass: ao is plain bf16) -> d_out ----
  gemm128_kernel<2,EPI_F32,false><<<gg, 256, 0, stream>>>(
      ao_hi, nullptr, whi + 7*NW, wlo + 7*NW, nullptr, bo, nullptr, 1.0f,
      (float*)d_out, nullptr, nullptr);
}

// Round 5
// 371.032 us; speedup vs baseline: 1.5640x; 1.1278x over previous
//
#include <hip/hip_runtime.h>
#include <math.h>

// ============================================================================
// TransformerEncoder_gram round 5:
//  - ALL 5 projection GEMMs merged into ONE launch (1280 blocks, 2/CU
//    co-resident) -> hides the vmcnt(0) barrier drain that made 5 separate
//    256-block launches latency-bound (1 block/CU, serialized stream).
//  - gate jobs: 2-pass v + 1-pass g (A-hi only), separate vacc1/vacc2.
//  - out-proj GEMM retiled 64x128 (512 blocks = 2/CU).
//  - attn: XCD-swizzled 1-D grid (same-bh blocks share an XCD L2).
// ============================================================================

typedef short bf16x8 __attribute__((ext_vector_type(8)));
typedef float f32x4  __attribute__((ext_vector_type(4)));

#define MFMA16(a,b,c) __builtin_amdgcn_mfma_f32_16x16x32_bf16((a),(b),(c),0,0,0)

static constexpr float LOG2E_F = 1.4426950408889634f;
static constexpr float CBRT_L2E = 1.12994722f;     // log2e^(1/3)
static constexpr float DEFER_THR = 11.54156033f;   // 8 * log2e
static constexpr float EPS_SCALED = 2.0813689e-8f; // 1e-8 * log2e^2

typedef const __attribute__((address_space(1))) unsigned int gas_u32;
typedef __attribute__((address_space(3))) unsigned int las_u32;

__device__ __forceinline__ void gload16(const void* g, void* l){
  __builtin_amdgcn_global_load_lds((gas_u32*)g, (las_u32*)l, 16, 0, 0);
}

__device__ __forceinline__ float b2f(unsigned short s){
  union { unsigned u; float f; } v; v.u = ((unsigned)s) << 16; return v.f;
}
__device__ __forceinline__ unsigned short f2b(float f){
  union { float f; unsigned u; } v; v.f = f;
  unsigned r = v.u + 0x7fffu + ((v.u >> 16) & 1u);
  return (unsigned short)(r >> 16);
}

// ---------------------------------------------------------------------------
// split fp32 -> (hi, lo) bf16 pair
// ---------------------------------------------------------------------------
__global__ __launch_bounds__(256) void split3_kernel(
    const float* __restrict__ a, const float* __restrict__ b,
    const float* __restrict__ c,
    unsigned short* __restrict__ hi, unsigned short* __restrict__ lo, int n)
{
  const int y = blockIdx.y;
  const float* src = (y == 0) ? a : ((y == 1) ? b : c);
  unsigned short* h = hi + (size_t)y * n;
  unsigned short* L = lo + (size_t)y * n;
  int stride = gridDim.x * 256;
  for (int i = blockIdx.x*256 + threadIdx.x; i < n; i += stride){
    float v = src[i];
    unsigned short hh = f2b(v);
    h[i] = hh;
    L[i] = f2b(v - b2f(hh));
  }
}

__global__ __launch_bounds__(256) void splitW_kernel(
    const float* w0, const float* w1, const float* w2, const float* w3,
    const float* w4, const float* w5, const float* w6, const float* w7,
    unsigned short* __restrict__ hi, unsigned short* __restrict__ lo, int n)
{
  const int y = blockIdx.y;
  const float* src = w0;
  if (y == 1) src = w1; if (y == 2) src = w2; if (y == 3) src = w3;
  if (y == 4) src = w4; if (y == 5) src = w5; if (y == 6) src = w6;
  if (y == 7) src = w7;
  unsigned short* h = hi + (size_t)y * n;
  unsigned short* L = lo + (size_t)y * n;
  int stride = gridDim.x * 256;
  for (int i = blockIdx.x*256 + threadIdx.x; i < n; i += stride){
    float v = src[i];
    unsigned short hh = f2b(v);
    h[i] = hh;
    L[i] = f2b(v - b2f(hh));
  }
}

// ---------------------------------------------------------------------------
// Merged projection GEMM: 128x128 tile, BK=32, dbuf global_load_lds.
// grid = (64, 20): job = y>>2, e0 = (y&3)*128.
//   job 0: q  = xq @ Wq   (3-pass, heads-epi, scale 0.125*cbrt)
//   job 1: k1 = x1 @ Wk1  (3-pass, heads-epi, scale cbrt)
//   job 2: k2 = x2 @ Wk2  (3-pass, heads-epi, scale cbrt)
//   job 3: vacc1 = (x1@Wv1+bv1)*sigmoid(x1@Wg1+bg1)  (2-pass v, 1-pass g)
//   job 4: vacc2 = (x2@Wv2+bv2)*sigmoid(x2@Wg2+bg2)
// LDS slots (4 x 4096 shorts, dbuf = 64 KB):
//   0: Ahi   1: Alo (jobs 0-2) / Bg-hi (jobs 3-4)   2: Bhi   3: Blo
// ---------------------------------------------------------------------------
__global__ __launch_bounds__(256,2) void proj_kernel(
    const unsigned short* __restrict__ xhi, const unsigned short* __restrict__ xlo,
    const unsigned short* __restrict__ whi, const unsigned short* __restrict__ wlo,
    const float* __restrict__ bq, const float* __restrict__ bk1,
    const float* __restrict__ bk2,
    const float* __restrict__ bv1, const float* __restrict__ bg1,
    const float* __restrict__ bv2, const float* __restrict__ bg2,
    unsigned short* __restrict__ qh_hi, unsigned short* __restrict__ qh_lo,
    unsigned short* __restrict__ k1h_hi, unsigned short* __restrict__ k1h_lo,
    unsigned short* __restrict__ k2h_hi, unsigned short* __restrict__ k2h_lo,
    float* __restrict__ vacc1, float* __restrict__ vacc2)
{
  __shared__ unsigned short smem[2*4*4096];
  const int tid = threadIdx.x, w = tid >> 6, l = tid & 63;
  const int y = blockIdx.y;
  const int job = y >> 2;
  const int r0 = blockIdx.x * 128, e0 = (y & 3) * 128;
  const int lrow = l & 15, kg = l >> 4;
  const bool isGate = (job >= 3);

  const size_t NXs = (size_t)8192*512, NWs = (size_t)512*512;
  const int aidx = (job == 0) ? 0 : ((job == 1 || job == 3) ? 1 : 2);
  const unsigned short* Ahi = xhi + (size_t)aidx * NXs;
  const unsigned short* Alo = xlo + (size_t)aidx * NXs;
  const int bidx = isGate ? ((job == 3) ? 3 : 4) : job;
  const unsigned short* Bhi = whi + (size_t)bidx * NWs;
  const unsigned short* Blo = wlo + (size_t)bidx * NWs;
  const unsigned short* Bg  = whi + (size_t)((job == 3) ? 5 : 6) * NWs;

  f32x4 acc[4][4], gacc[4][4];
  #pragma unroll
  for (int m = 0; m < 4; ++m)
    #pragma unroll
    for (int n = 0; n < 4; ++n){
      acc[m][n] = (f32x4){0.f,0.f,0.f,0.f};
      gacc[m][n] = (f32x4){0.f,0.f,0.f,0.f};
    }

  const int sgsw = ((l & 3) ^ ((l >> 3) & 3)) * 8;
  const int srA = r0 + w*16 + (l >> 2);
  const int srB = e0 + w*16 + (l >> 2);

  auto stage = [&](int buf, int kk){
    const int lb = buf*4*4096 + w*512;
    #pragma unroll
    for (int j = 0; j < 2; ++j){
      const size_t ga = (size_t)(srA + j*64)*512 + kk + sgsw;
      const size_t gb = (size_t)(srB + j*64)*512 + kk + sgsw;
      gload16(&Ahi[ga], &smem[lb + 0*4096 + j*2048]);
      if (!isGate) gload16(&Alo[ga], &smem[lb + 1*4096 + j*2048]);
      else         gload16(&Bg[gb],  &smem[lb + 1*4096 + j*2048]);
      gload16(&Bhi[gb], &smem[lb + 2*4096 + j*2048]);
      gload16(&Blo[gb], &smem[lb + 3*4096 + j*2048]);
    }
  };

  const int rowA = (w >> 1)*64 + lrow;
  const int rowB = (w & 1)*64 + lrow;
  const int kgs  = (kg ^ ((lrow >> 1) & 3)) * 8;

  auto compute = [&](int buf){
    const int bb = buf*4*4096;
    bf16x8 ah[4], al[4];
    #pragma unroll
    for (int m = 0; m < 4; ++m){
      const int ra = (rowA + m*16)*32 + kgs;
      ah[m] = *(const bf16x8*)&smem[bb + ra];
      if (!isGate) al[m] = *(const bf16x8*)&smem[bb + 4096 + ra];
    }
    #pragma unroll
    for (int n = 0; n < 4; ++n){
      const int rb = (rowB + n*16)*32 + kgs;
      bf16x8 bh = *(const bf16x8*)&smem[bb + 8192 + rb];
      bf16x8 bl = *(const bf16x8*)&smem[bb + 12288 + rb];
      #pragma unroll
      for (int m = 0; m < 4; ++m){
        acc[m][n] = MFMA16(ah[m], bh, acc[m][n]);
        acc[m][n] = MFMA16(ah[m], bl, acc[m][n]);
      }
      if (!isGate){
        #pragma unroll
        for (int m = 0; m < 4; ++m)
          acc[m][n] = MFMA16(al[m], bh, acc[m][n]);
      } else {
        bf16x8 bg = *(const bf16x8*)&smem[bb + 4096 + rb];
        #pragma unroll
        for (int m = 0; m < 4; ++m)
          gacc[m][n] = MFMA16(ah[m], bg, gacc[m][n]);
      }
    }
  };

  stage(0, 0);
  __syncthreads();
  for (int t = 0; t < 16; ++t){
    if (t < 15) stage((t+1) & 1, (t+1)*32);
    compute(t & 1);
    __syncthreads();
  }

  if (!isGate){
    const float* bias = (job == 0) ? bq : ((job == 1) ? bk1 : bk2);
    const float scale = (job == 0) ? 0.125f*CBRT_L2E : CBRT_L2E;
    unsigned short* oH = (job == 0) ? qh_hi : ((job == 1) ? k1h_hi : k2h_hi);
    unsigned short* oL = (job == 0) ? qh_lo : ((job == 1) ? k1h_lo : k2h_lo);
    #pragma unroll
    for (int n = 0; n < 4; ++n){
      const int e = e0 + (w & 1)*64 + n*16 + lrow;
      const float bv = bias[e];
      #pragma unroll
      for (int m = 0; m < 4; ++m){
        #pragma unroll
        for (int q = 0; q < 4; ++q){
          const int r = r0 + (w >> 1)*64 + m*16 + kg*4 + q;
          const float yv = (acc[m][n][q] + bv) * scale;
          const int bh = ((r & 7) << 3) + (e >> 6);
          const size_t off = ((size_t)bh*1024 + (r >> 3))*64 + (e & 63);
          unsigned short hh = f2b(yv);
          oH[off] = hh;
          oL[off] = f2b(yv - b2f(hh));
        }
      }
    }
  } else {
    const float* bvv = (job == 3) ? bv1 : bv2;
    const float* bgg = (job == 3) ? bg1 : bg2;
    float* outF = (job == 3) ? vacc1 : vacc2;
    #pragma unroll
    for (int n = 0; n < 4; ++n){
      const int e = e0 + (w & 1)*64 + n*16 + lrow;
      const float bv = bvv[e], bg_ = bgg[e];
      #pragma unroll
      for (int m = 0; m < 4; ++m){
        #pragma unroll
        for (int q = 0; q < 4; ++q){
          const int r = r0 + (w >> 1)*64 + m*16 + kg*4 + q;
          const float yv = acc[m][n][q] + bv;
          const float yg = gacc[m][n][q] + bg_;
          const float sg = 1.0f / (1.0f + exp2f(-yg * LOG2E_F));
          outF[(size_t)r*512 + e] = yv * sg;
        }
      }
    }
  }
}

// ---------------------------------------------------------------------------
// Out projection: 64x128 tile (grid 128x4 = 512 blocks, 2/CU), 2-pass.
// LDS: A(2048) + Bhi(4096) + Blo(4096) shorts, dbuf = 40 KB.
// ---------------------------------------------------------------------------
__global__ __launch_bounds__(256,2) void gemmout_kernel(
    const unsigned short* __restrict__ Ahi,
    const unsigned short* __restrict__ Bhi, const unsigned short* __restrict__ Blo,
    const float* __restrict__ bias, float* __restrict__ outF)
{
  __shared__ unsigned short smem[2*10240];
  const int tid = threadIdx.x, w = tid >> 6, l = tid & 63;
  const int r0 = blockIdx.x * 64, e0 = blockIdx.y * 128;
  const int lrow = l & 15, kg = l >> 4;

  f32x4 acc[2][4];
  #pragma unroll
  for (int m = 0; m < 2; ++m)
    #pragma unroll
    for (int n = 0; n < 4; ++n) acc[m][n] = (f32x4){0.f,0.f,0.f,0.f};

  const int sgsw = ((l & 3) ^ ((l >> 3) & 3)) * 8;
  const int srA = r0 + w*16 + (l >> 2);
  const int srB = e0 + w*16 + (l >> 2);

  auto stage = [&](int buf, int kk){
    const int lb = buf*10240;
    gload16(&Ahi[(size_t)srA*512 + kk + sgsw], &smem[lb + tid*8]);
    #pragma unroll
    for (int j = 0; j < 2; ++j){
      const size_t gb = (size_t)(srB + j*64)*512 + kk + sgsw;
      gload16(&Bhi[gb], &smem[lb + 2048 + (tid + j*256)*8]);
      gload16(&Blo[gb], &smem[lb + 6144 + (tid + j*256)*8]);
    }
  };

  const int rowA = (w >> 1)*32 + lrow;
  const int rowB = (w & 1)*64 + lrow;
  const int kgs  = (kg ^ ((lrow >> 1) & 3)) * 8;

  auto compute = [&](int buf){
    const int bb = buf*10240;
    bf16x8 ah[2];
    #pragma unroll
    for (int m = 0; m < 2; ++m)
      ah[m] = *(const bf16x8*)&smem[bb + (rowA + m*16)*32 + kgs];
    #pragma unroll
    for (int n = 0; n < 4; ++n){
      const int rb = (rowB + n*16)*32 + kgs;
      bf16x8 bh = *(const bf16x8*)&smem[bb + 2048 + rb];
      bf16x8 bl = *(const bf16x8*)&smem[bb + 6144 + rb];
      #pragma unroll
      for (int m = 0; m < 2; ++m){
        acc[m][n] = MFMA16(ah[m], bh, acc[m][n]);
        acc[m][n] = MFMA16(ah[m], bl, acc[m][n]);
      }
    }
  };

  stage(0, 0);
  __syncthreads();
  for (int t = 0; t < 16; ++t){
    if (t < 15) stage((t+1) & 1, (t+1)*32);
    compute(t & 1);
    __syncthreads();
  }

  #pragma unroll
  for (int n = 0; n < 4; ++n){
    const int e = e0 + (w & 1)*64 + n*16 + lrow;
    const float bv = bias[e];
    #pragma unroll
    for (int m = 0; m < 2; ++m){
      #pragma unroll
      for (int q = 0; q < 4; ++q){
        const int r = r0 + (w >> 1)*32 + m*16 + kg*4 + q;
        outF[(size_t)r*512 + e] = acc[m][n][q] + bv;
      }
    }
  }
}

// ---------------------------------------------------------------------------
// Per-(bh,t): ll=|q|^2 and packed {cross, aa, 2va, vv} (fp32)
// ---------------------------------------------------------------------------
__global__ __launch_bounds__(256) void norms_kernel(
    const unsigned short* __restrict__ qh, const unsigned short* __restrict__ ql,
    const unsigned short* __restrict__ k1h, const unsigned short* __restrict__ k1l,
    const unsigned short* __restrict__ k2h, const unsigned short* __restrict__ k2l,
    float* __restrict__ ll, f32x4* __restrict__ nrm4)
{
  const int idx = blockIdx.x*256 + threadIdx.x;
  const size_t base = (size_t)idx * 64;
  float sll = 0.f, svv = 0.f, saa = 0.f, sva = 0.f;
  #pragma unroll
  for (int j = 0; j < 8; ++j){
    bf16x8 q_h = *(const bf16x8*)&qh[base + j*8];
    bf16x8 q_l = *(const bf16x8*)&ql[base + j*8];
    bf16x8 a_h = *(const bf16x8*)&k1h[base + j*8];
    bf16x8 a_l = *(const bf16x8*)&k1l[base + j*8];
    bf16x8 c_h = *(const bf16x8*)&k2h[base + j*8];
    bf16x8 c_l = *(const bf16x8*)&k2l[base + j*8];
    #pragma unroll
    for (int i = 0; i < 8; ++i){
      float qv = b2f((unsigned short)q_h[i]) + b2f((unsigned short)q_l[i]);
      float a1 = b2f((unsigned short)a_h[i]) + b2f((unsigned short)a_l[i]);
      float a2 = b2f((unsigned short)c_h[i]) + b2f((unsigned short)c_l[i]);
      sll += qv*qv; svv += a1*a1; saa += a2*a2; sva += a1*a2;
    }
  }
  ll[idx] = sll;
  nrm4[idx] = (f32x4){svv*saa - sva*sva, saa, 2.0f*sva, svv};
}

// ---------------------------------------------------------------------------
// (vacc1 + vacc2) fp32 [r][e] -> transposed bf16 vT[bh][d][s]
// ---------------------------------------------------------------------------
__global__ __launch_bounds__(256) void vtrans_kernel(
    const float* __restrict__ v1, const float* __restrict__ v2,
    unsigned short* __restrict__ vTh)
{
  __shared__ unsigned short sH[64*64];
  const int bh = blockIdx.y, b = bh >> 3, h = bh & 7;
  const int s0 = blockIdx.x * 64;
  const int tid = threadIdx.x;
  for (int c = tid; c < 1024; c += 256){
    const int i = c >> 4, sl = c & 15;
    const size_t g = ((size_t)(s0 + i)*8 + b)*512 + h*64 + sl*4;
    f32x4 a = *(const f32x4*)&v1[g];
    f32x4 bb = *(const f32x4*)&v2[g];
    #pragma unroll
    for (int e = 0; e < 4; ++e)
      sH[(sl*4 + e)*64 + i] = f2b(a[e] + bb[e]);
  }
  __syncthreads();
  for (int c = tid; c < 512; c += 256){
    const int d = c >> 3, sl = c & 7;
    const size_t g = ((size_t)bh*64 + d)*1024 + s0 + sl*8;
    *(bf16x8*)&vTh[g] = *(const bf16x8*)&sH[d*64 + sl*8];
  }
}

// ---------------------------------------------------------------------------
// Fused gram-det attention. QBLK=128 (4 waves x 32 rows), KVBLK=64.
// 1-D grid 512, XCD-swizzled: bh = blk & 63 (same-bh blocks share an XCD).
// ---------------------------------------------------------------------------
__global__ __launch_bounds__(256,2) void attn_kernel(
    const unsigned short* __restrict__ qhh, const unsigned short* __restrict__ qhl,
    const unsigned short* __restrict__ k1hh, const unsigned short* __restrict__ k1hl,
    const unsigned short* __restrict__ k2hh, const unsigned short* __restrict__ k2hl,
    const unsigned short* __restrict__ vTh,
    const float* __restrict__ llv, const f32x4* __restrict__ nrm4,
    unsigned short* __restrict__ aoHi)
{
  __shared__ unsigned short sK1h[4096];
  __shared__ unsigned short sK1l[4096];
  __shared__ unsigned short sK2h[4096];
  __shared__ unsigned short sK2l[4096];
  __shared__ unsigned short sVh[4096];
  __shared__ unsigned short sPh[8192];
  __shared__ f32x4 sN4[64];

  const int bh = blockIdx.x & 63, l0 = (blockIdx.x >> 6) * 128;
  const int tid = threadIdx.x, w = tid >> 6, lane = tid & 63;
  const int lrow = lane & 15, kg = lane >> 4;

  bf16x8 qfh[2][2], qfl[2][2];
  #pragma unroll
  for (int m = 0; m < 2; ++m){
    const size_t qb = ((size_t)bh*1024 + l0 + w*32 + m*16 + lrow)*64 + kg*8;
    qfh[m][0] = *(const bf16x8*)&qhh[qb];
    qfl[m][0] = *(const bf16x8*)&qhl[qb];
    qfh[m][1] = *(const bf16x8*)&qhh[qb + 32];
    qfl[m][1] = *(const bf16x8*)&qhl[qb + 32];
  }
  float ll_r[2][4];
  #pragma unroll
  for (int m = 0; m < 2; ++m)
    #pragma unroll
    for (int q = 0; q < 4; ++q)
      ll_r[m][q] = llv[bh*1024 + l0 + w*32 + m*16 + kg*4 + q];

  f32x4 accO[2][4];
  #pragma unroll
  for (int m = 0; m < 2; ++m)
    #pragma unroll
    for (int i = 0; i < 4; ++i) accO[m][i] = (f32x4){0.f,0.f,0.f,0.f};
  float mn[2][4], s_run[2][4];
  #pragma unroll
  for (int m = 0; m < 2; ++m)
    #pragma unroll
    for (int q = 0; q < 4; ++q){ mn[m][q] = 1e30f; s_run[m][q] = 0.f; }

  const int c0 = tid, c1 = tid + 256;
  const int r0g = c0 >> 3, g0 = ((c0 & 7) ^ (r0g & 7)) * 8;
  const int r1g = c1 >> 3, g1 = ((c1 & 7) ^ (r1g & 7)) * 8;

  for (int ss = 0; ss < 1024; ss += 64){
    {
      const size_t kb = (size_t)bh*1024 + ss;
      const size_t k0 = (kb + r0g)*64 + g0;
      const size_t k1_ = (kb + r1g)*64 + g1;
      gload16(&k1hh[k0], &sK1h[c0*8]);  gload16(&k1hh[k1_], &sK1h[c1*8]);
      gload16(&k1hl[k0], &sK1l[c0*8]);  gload16(&k1hl[k1_], &sK1l[c1*8]);
      gload16(&k2hh[k0], &sK2h[c0*8]);  gload16(&k2hh[k1_], &sK2h[c1*8]);
      gload16(&k2hl[k0], &sK2l[c0*8]);  gload16(&k2hl[k1_], &sK2l[c1*8]);
      const size_t v0 = ((size_t)bh*64 + r0g)*1024 + ss + g0;
      const size_t v1 = ((size_t)bh*64 + r1g)*1024 + ss + g1;
      gload16(&vTh[v0], &sVh[c0*8]);    gload16(&vTh[v1], &sVh[c1*8]);
      if (tid < 64) gload16(&nrm4[(size_t)bh*1024 + ss + tid], &sN4[tid]);
    }
    __syncthreads();

    float p_[2][4][4];
    float tmn[2][4];
    #pragma unroll
    for (int m = 0; m < 2; ++m)
      #pragma unroll
      for (int q = 0; q < 4; ++q) tmn[m][q] = 1e30f;

    #pragma unroll
    for (int nt = 0; nt < 4; ++nt){
      f32x4 lv[2], la[2];
      #pragma unroll
      for (int m = 0; m < 2; ++m){ lv[m] = (f32x4){0.f,0.f,0.f,0.f}; la[m] = (f32x4){0.f,0.f,0.f,0.f}; }
      #pragma unroll
      for (int ks = 0; ks < 2; ++ks){
        const int row = nt*16 + lrow;
        const int off = row*64 + (((ks*4 + kg) ^ (row & 7)) * 8);
        bf16x8 b1h = *(const bf16x8*)&sK1h[off];
        bf16x8 b1l = *(const bf16x8*)&sK1l[off];
        bf16x8 b2h = *(const bf16x8*)&sK2h[off];
        bf16x8 b2l = *(const bf16x8*)&sK2l[off];
        #pragma unroll
        for (int m = 0; m < 2; ++m){
          lv[m] = MFMA16(qfh[m][ks], b1h, lv[m]);
          lv[m] = MFMA16(qfh[m][ks], b1l, lv[m]);
          lv[m] = MFMA16(qfl[m][ks], b1h, lv[m]);
          la[m] = MFMA16(qfh[m][ks], b2h, la[m]);
          la[m] = MFMA16(qfh[m][ks], b2l, la[m]);
          la[m] = MFMA16(qfl[m][ks], b2h, la[m]);
        }
      }
      f32x4 n4 = sN4[nt*16 + lrow];
      const float cross = n4[0], c_aa = n4[1], c_va2 = n4[2], c_vv = n4[3];
      #pragma unroll
      for (int m = 0; m < 2; ++m){
        #pragma unroll
        for (int q = 0; q < 4; ++q){
          const float flv = lv[m][q], fla = la[m][q];
          float t = fmaf(-c_vv, fla*fla, (flv*fla)*c_va2);
          t = fmaf(-c_aa, flv*flv, t);
          const float det = fmaf(ll_r[m][q], cross, t);
          const float sq = __builtin_amdgcn_sqrtf(fmaxf(det, EPS_SCALED));
          p_[m][nt][q] = sq;
          tmn[m][q] = fminf(tmn[m][q], sq);
        }
      }
    }
    #pragma unroll
    for (int m = 0; m < 2; ++m)
      #pragma unroll
      for (int q = 0; q < 4; ++q){
        tmn[m][q] = fminf(tmn[m][q], __shfl_xor(tmn[m][q], 1));
        tmn[m][q] = fminf(tmn[m][q], __shfl_xor(tmn[m][q], 2));
        tmn[m][q] = fminf(tmn[m][q], __shfl_xor(tmn[m][q], 4));
        tmn[m][q] = fminf(tmn[m][q], __shfl_xor(tmn[m][q], 8));
      }
    int up = 0;
    #pragma unroll
    for (int m = 0; m < 2; ++m)
      #pragma unroll
      for (int q = 0; q < 4; ++q) up |= (tmn[m][q] < mn[m][q] - DEFER_THR) ? 1 : 0;
    if (__any(up)){
      #pragma unroll
      for (int m = 0; m < 2; ++m)
        #pragma unroll
        for (int q = 0; q < 4; ++q){
          const float mnn = fminf(mn[m][q], tmn[m][q]);
          const float rs = __builtin_amdgcn_exp2f(mnn - mn[m][q]);
          mn[m][q] = mnn;
          s_run[m][q] *= rs;
          #pragma unroll
          for (int dt = 0; dt < 4; ++dt) accO[m][dt][q] *= rs;
        }
    }
    float ps[2][4];
    #pragma unroll
    for (int m = 0; m < 2; ++m)
      #pragma unroll
      for (int q = 0; q < 4; ++q) ps[m][q] = 0.f;
    #pragma unroll
    for (int nt = 0; nt < 4; ++nt)
      #pragma unroll
      for (int m = 0; m < 2; ++m)
        #pragma unroll
        for (int q = 0; q < 4; ++q){
          const float e = __builtin_amdgcn_exp2f(mn[m][q] - p_[m][nt][q]);
          p_[m][nt][q] = e;
          ps[m][q] += e;
        }
    #pragma unroll
    for (int m = 0; m < 2; ++m)
      #pragma unroll
      for (int q = 0; q < 4; ++q){
        float v = ps[m][q];
        v += __shfl_xor(v, 1); v += __shfl_xor(v, 2);
        v += __shfl_xor(v, 4); v += __shfl_xor(v, 8);
        s_run[m][q] += v;
      }

    #pragma unroll
    for (int m = 0; m < 2; ++m){
      #pragma unroll
      for (int nt = 0; nt < 4; ++nt){
        const int col = nt*16 + lrow;
        const int cg = col >> 3, cr = col & 7;
        #pragma unroll
        for (int qp = 0; qp < 2; ++qp){
          unsigned int pk;
          asm("v_cvt_pk_bf16_f32 %0, %1, %2" : "=v"(pk)
              : "v"(p_[m][nt][qp*2]), "v"(p_[m][nt][qp*2+1]));
          const int ra = m*16 + kg*4 + qp*2, rb = ra + 1;
          sPh[w*2048 + ra*64 + ((cg ^ (ra & 7))*8) + cr] = (unsigned short)(pk & 0xffffu);
          sPh[w*2048 + rb*64 + ((cg ^ (rb & 7))*8) + cr] = (unsigned short)(pk >> 16);
        }
      }
    }

    #pragma unroll
    for (int ks = 0; ks < 2; ++ks){
      bf16x8 pa[2];
      #pragma unroll
      for (int m = 0; m < 2; ++m){
        const int prow = m*16 + lrow;
        pa[m] = *(const bf16x8*)&sPh[w*2048 + prow*64 + (((ks*4 + kg) ^ (prow & 7))*8)];
      }
      #pragma unroll
      for (int dt = 0; dt < 4; ++dt){
        const int vrow = dt*16 + lrow;
        bf16x8 bvh = *(const bf16x8*)&sVh[vrow*64 + (((ks*4 + kg) ^ (vrow & 7))*8)];
        #pragma unroll
        for (int m = 0; m < 2; ++m)
          accO[m][dt] = MFMA16(pa[m], bvh, accO[m][dt]);
      }
    }
    __syncthreads();
  }

  const int b = bh >> 3, h = bh & 7;
  #pragma unroll
  for (int m = 0; m < 2; ++m){
    float rcp[4];
    #pragma unroll
    for (int q = 0; q < 4; ++q) rcp[q] = __builtin_amdgcn_rcpf(s_run[m][q]);
    #pragma unroll
    for (int dt = 0; dt < 4; ++dt){
      const int d = dt*16 + lrow;
      #pragma unroll
      for (int q = 0; q < 4; ++q){
        const int l_ = l0 + w*32 + m*16 + kg*4 + q;
        aoHi[((size_t)l_*8 + b)*512 + h*64 + d] = f2b(accO[m][dt][q] * rcp[q]);
      }
    }
  }
}

// ===========================================================================
extern "C" void kernel_launch(void* const* d_in, const int* in_sizes, int n_in,
                              void* d_out, int out_size, void* d_ws, size_t ws_size,
                              hipStream_t stream)
{
  const float* query = (const float*)d_in[0];
  const float* mod1  = (const float*)d_in[1];
  const float* mod2  = (const float*)d_in[2];
  const float* bq  = (const float*)d_in[4];
  const float* bk1 = (const float*)d_in[6];
  const float* bk2 = (const float*)d_in[8];
  const float* bv1 = (const float*)d_in[10];
  const float* bv2 = (const float*)d_in[12];
  const float* bg1 = (const float*)d_in[14];
  const float* bg2 = (const float*)d_in[16];
  const float* bo  = (const float*)d_in[18];

  char* p = (char*)d_ws;
  auto take = [&](size_t bytes) -> char* {
    char* r = p; p += (bytes + 255) & ~(size_t)255; return r;
  };
  const size_t NX = (size_t)8192*512;
  const size_t NW = (size_t)512*512;
  const size_t XB = NX*2, WB = NW*2;
  const size_t HB = (size_t)64*1024*64*2;
  const size_t FB = NX*4;
  const size_t NB = (size_t)64*1024*4;

  unsigned short* xhi = (unsigned short*)take(3*XB);
  unsigned short* xlo = (unsigned short*)take(3*XB);
  unsigned short* whi = (unsigned short*)take(8*WB);
  unsigned short* wlo = (unsigned short*)take(8*WB);
  unsigned short* qh_hi  = (unsigned short*)take(HB);
  unsigned short* qh_lo  = (unsigned short*)take(HB);
  unsigned short* k1h_hi = (unsigned short*)take(HB);
  unsigned short* k1h_lo = (unsigned short*)take(HB);
  unsigned short* k2h_hi = (unsigned short*)take(HB);
  unsigned short* k2h_lo = (unsigned short*)take(HB);
  unsigned short* vT_hi  = (unsigned short*)take(HB);
  float* vacc1 = (float*)take(FB);
  float* vacc2 = (float*)take(FB);
  unsigned short* ao_hi = (unsigned short*)take(HB);
  float* llv = (float*)take(NB);
  f32x4* nrm4 = (f32x4*)take(4*NB);

  // ---- 1. splits ----
  split3_kernel<<<dim3(1024,3), 256, 0, stream>>>(query, mod1, mod2, xhi, xlo, (int)NX);
  splitW_kernel<<<dim3(256,8), 256, 0, stream>>>(
      (const float*)d_in[3], (const float*)d_in[5], (const float*)d_in[7],
      (const float*)d_in[9], (const float*)d_in[11], (const float*)d_in[13],
      (const float*)d_in[15], (const float*)d_in[17], whi, wlo, (int)NW);

  // ---- 2. ALL projections in one launch (1280 blocks) ----
  proj_kernel<<<dim3(64, 20), 256, 0, stream>>>(
      xhi, xlo, whi, wlo, bq, bk1, bk2, bv1, bg1, bv2, bg2,
      qh_hi, qh_lo, k1h_hi, k1h_lo, k2h_hi, k2h_lo, vacc1, vacc2);

  // ---- 3. gram scalars + gated-V transpose ----
  norms_kernel<<<256, 256, 0, stream>>>(qh_hi, qh_lo, k1h_hi, k1h_lo,
                                        k2h_hi, k2h_lo, llv, nrm4);
  vtrans_kernel<<<dim3(16, 64), 256, 0, stream>>>(vacc1, vacc2, vT_hi);

  // ---- 4. fused gram-det attention (XCD-swizzled 1-D grid) ----
  attn_kernel<<<512, 256, 0, stream>>>(
      qh_hi, qh_lo, k1h_hi, k1h_lo, k2h_hi, k2h_lo, vT_hi,
      llv, nrm4, ao_hi);

  // ---- 5. output projection (64x128 tiles, 512 blocks) -> d_out ----
  gemmout_kernel<<<dim3(128, 4), 256, 0, stream>>>(
      ao_hi, whi + 7*NW, wlo + 7*NW, bo, (float*)d_out);
}

// Round 6
// 349.902 us; speedup vs baseline: 1.6585x; 1.0604x over previous
//
#include <hip/hip_runtime.h>
#include <math.h>

// ============================================================================
// TransformerEncoder_gram round 6:
//  - proj GEMMs cut 3-pass -> 2-pass (q/k1/k2, single-acc) and 1-pass (v,g):
//    projection-output errors enter scores as random walks (analysis in log),
//    unlike in-attn QK pass-dropping (correlated logit shift, rejected).
//  - proj split: qk kernel (768 blk, 1 acc, 48KB, 3/CU) + vg kernel (512 blk).
//  - x-lo buffers now unused -> split3 becomes pure fp32->bf16 cast.
//  - attn: s_setprio(1) around MFMA clusters (T5).
// ============================================================================

typedef short bf16x8 __attribute__((ext_vector_type(8)));
typedef float f32x4  __attribute__((ext_vector_type(4)));

#define MFMA16(a,b,c) __builtin_amdgcn_mfma_f32_16x16x32_bf16((a),(b),(c),0,0,0)

static constexpr float LOG2E_F = 1.4426950408889634f;
static constexpr float CBRT_L2E = 1.12994722f;     // log2e^(1/3)
static constexpr float DEFER_THR = 11.54156033f;   // 8 * log2e
static constexpr float EPS_SCALED = 2.0813689e-8f; // 1e-8 * log2e^2

typedef const __attribute__((address_space(1))) unsigned int gas_u32;
typedef __attribute__((address_space(3))) unsigned int las_u32;

__device__ __forceinline__ void gload16(const void* g, void* l){
  __builtin_amdgcn_global_load_lds((gas_u32*)g, (las_u32*)l, 16, 0, 0);
}

__device__ __forceinline__ float b2f(unsigned short s){
  union { unsigned u; float f; } v; v.u = ((unsigned)s) << 16; return v.f;
}
__device__ __forceinline__ unsigned short f2b(float f){
  union { float f; unsigned u; } v; v.f = f;
  unsigned r = v.u + 0x7fffu + ((v.u >> 16) & 1u);
  return (unsigned short)(r >> 16);
}

// ---------------------------------------------------------------------------
// cast fp32 -> bf16 (hi only; proj is 2-pass on B so A-lo is unused)
// ---------------------------------------------------------------------------
__global__ __launch_bounds__(256) void cast3_kernel(
    const float* __restrict__ a, const float* __restrict__ b,
    const float* __restrict__ c, unsigned short* __restrict__ hi, int n)
{
  const int y = blockIdx.y;
  const float* src = (y == 0) ? a : ((y == 1) ? b : c);
  unsigned short* h = hi + (size_t)y * n;
  const int n8 = n >> 3;
  int stride = gridDim.x * 256;
  for (int i = blockIdx.x*256 + threadIdx.x; i < n8; i += stride){
    f32x4 v0 = *(const f32x4*)&src[i*8];
    f32x4 v1 = *(const f32x4*)&src[i*8 + 4];
    bf16x8 o;
    #pragma unroll
    for (int j = 0; j < 4; ++j){
      o[j]   = (short)f2b(v0[j]);
      o[j+4] = (short)f2b(v1[j]);
    }
    *(bf16x8*)&h[i*8] = o;
  }
}

__global__ __launch_bounds__(256) void splitW_kernel(
    const float* w0, const float* w1, const float* w2, const float* w3,
    const float* w4, const float* w5, const float* w6, const float* w7,
    unsigned short* __restrict__ hi, unsigned short* __restrict__ lo, int n)
{
  const int y = blockIdx.y;
  const float* src = w0;
  if (y == 1) src = w1; if (y == 2) src = w2; if (y == 3) src = w3;
  if (y == 4) src = w4; if (y == 5) src = w5; if (y == 6) src = w6;
  if (y == 7) src = w7;
  unsigned short* h = hi + (size_t)y * n;
  unsigned short* L = lo + (size_t)y * n;
  int stride = gridDim.x * 256;
  for (int i = blockIdx.x*256 + threadIdx.x; i < n; i += stride){
    float v = src[i];
    unsigned short hh = f2b(v);
    h[i] = hh;
    L[i] = f2b(v - b2f(hh));
  }
}

// ---------------------------------------------------------------------------
// q/k1/k2 projections: 128x128 tile, BK=32, dbuf gload_lds, 2-pass single acc.
// grid (64, 12): job = y>>2 in {0,1,2}, e0 = (y&3)*128.  LDS 48 KB, 3 blk/CU.
// ---------------------------------------------------------------------------
__global__ __launch_bounds__(256,3) void proj_qk_kernel(
    const unsigned short* __restrict__ xhi,
    const unsigned short* __restrict__ whi, const unsigned short* __restrict__ wlo,
    const float* __restrict__ bq, const float* __restrict__ bk1,
    const float* __restrict__ bk2,
    unsigned short* __restrict__ qh_hi, unsigned short* __restrict__ qh_lo,
    unsigned short* __restrict__ k1h_hi, unsigned short* __restrict__ k1h_lo,
    unsigned short* __restrict__ k2h_hi, unsigned short* __restrict__ k2h_lo)
{
  __shared__ unsigned short smem[2*3*4096];
  const int tid = threadIdx.x, w = tid >> 6, l = tid & 63;
  const int y = blockIdx.y, job = y >> 2;
  const int r0 = blockIdx.x * 128, e0 = (y & 3) * 128;
  const int lrow = l & 15, kg = l >> 4;

  const size_t NXs = (size_t)8192*512, NWs = (size_t)512*512;
  const unsigned short* Ahi = xhi + (size_t)job * NXs;
  const unsigned short* B1  = whi + (size_t)job * NWs;
  const unsigned short* B2  = wlo + (size_t)job * NWs;

  f32x4 acc[4][4];
  #pragma unroll
  for (int m = 0; m < 4; ++m)
    #pragma unroll
    for (int n = 0; n < 4; ++n) acc[m][n] = (f32x4){0.f,0.f,0.f,0.f};

  const int sgsw = ((l & 3) ^ ((l >> 3) & 3)) * 8;
  const int srA = r0 + w*16 + (l >> 2);
  const int srB = e0 + w*16 + (l >> 2);

  auto stage = [&](int buf, int kk){
    const int lb = buf*3*4096 + w*512;
    #pragma unroll
    for (int j = 0; j < 2; ++j){
      const size_t ga = (size_t)(srA + j*64)*512 + kk + sgsw;
      const size_t gb = (size_t)(srB + j*64)*512 + kk + sgsw;
      gload16(&Ahi[ga], &smem[lb + 0    + j*2048]);
      gload16(&B1[gb],  &smem[lb + 4096 + j*2048]);
      gload16(&B2[gb],  &smem[lb + 8192 + j*2048]);
    }
  };

  const int rowA = (w >> 1)*64 + lrow;
  const int rowB = (w & 1)*64 + lrow;
  const int kgs  = (kg ^ ((lrow >> 1) & 3)) * 8;

  auto compute = [&](int buf){
    const int bb = buf*3*4096;
    bf16x8 ah[4];
    #pragma unroll
    for (int m = 0; m < 4; ++m)
      ah[m] = *(const bf16x8*)&smem[bb + (rowA + m*16)*32 + kgs];
    #pragma unroll
    for (int n = 0; n < 4; ++n){
      const int rb = (rowB + n*16)*32 + kgs;
      bf16x8 b1 = *(const bf16x8*)&smem[bb + 4096 + rb];
      bf16x8 b2 = *(const bf16x8*)&smem[bb + 8192 + rb];
      #pragma unroll
      for (int m = 0; m < 4; ++m){
        acc[m][n] = MFMA16(ah[m], b1, acc[m][n]);
        acc[m][n] = MFMA16(ah[m], b2, acc[m][n]);
      }
    }
  };

  stage(0, 0);
  __syncthreads();
  for (int t = 0; t < 16; ++t){
    if (t < 15) stage((t+1) & 1, (t+1)*32);
    compute(t & 1);
    __syncthreads();
  }

  const float* bias = (job == 0) ? bq : ((job == 1) ? bk1 : bk2);
  const float scale = (job == 0) ? 0.125f*CBRT_L2E : CBRT_L2E;
  unsigned short* oH = (job == 0) ? qh_hi : ((job == 1) ? k1h_hi : k2h_hi);
  unsigned short* oL = (job == 0) ? qh_lo : ((job == 1) ? k1h_lo : k2h_lo);
  #pragma unroll
  for (int n = 0; n < 4; ++n){
    const int e = e0 + (w & 1)*64 + n*16 + lrow;
    const float bv = bias[e];
    #pragma unroll
    for (int m = 0; m < 4; ++m){
      #pragma unroll
      for (int q = 0; q < 4; ++q){
        const int r = r0 + (w >> 1)*64 + m*16 + kg*4 + q;
        const float yv = (acc[m][n][q] + bv) * scale;
        const int bh = ((r & 7) << 3) + (e >> 6);
        const size_t off = ((size_t)bh*1024 + (r >> 3))*64 + (e & 63);
        unsigned short hh = f2b(yv);
        oH[off] = hh;
        oL[off] = f2b(yv - b2f(hh));
      }
    }
  }
}

// ---------------------------------------------------------------------------
// gated-v projections: v 1-pass + gate 1-pass (dual acc).
// grid (64, 8): job = 3 + (y>>2), e0 = (y&3)*128.  LDS 48 KB.
// ---------------------------------------------------------------------------
__global__ __launch_bounds__(256,2) void proj_vg_kernel(
    const unsigned short* __restrict__ xhi,
    const unsigned short* __restrict__ whi,
    const float* __restrict__ bv1, const float* __restrict__ bg1,
    const float* __restrict__ bv2, const float* __restrict__ bg2,
    float* __restrict__ vacc1, float* __restrict__ vacc2)
{
  __shared__ unsigned short smem[2*3*4096];
  const int tid = threadIdx.x, w = tid >> 6, l = tid & 63;
  const int y = blockIdx.y, job = 3 + (y >> 2);
  const int r0 = blockIdx.x * 128, e0 = (y & 3) * 128;
  const int lrow = l & 15, kg = l >> 4;

  const size_t NXs = (size_t)8192*512, NWs = (size_t)512*512;
  const unsigned short* Ahi = xhi + (size_t)(job - 2) * NXs;     // x1 or x2
  const unsigned short* B1  = whi + (size_t)((job == 3) ? 3 : 4) * NWs; // Wv
  const unsigned short* B2  = whi + (size_t)((job == 3) ? 5 : 6) * NWs; // Wg

  f32x4 acc[4][4], acc2[4][4];
  #pragma unroll
  for (int m = 0; m < 4; ++m)
    #pragma unroll
    for (int n = 0; n < 4; ++n){
      acc[m][n] = (f32x4){0.f,0.f,0.f,0.f};
      acc2[m][n] = (f32x4){0.f,0.f,0.f,0.f};
    }

  const int sgsw = ((l & 3) ^ ((l >> 3) & 3)) * 8;
  const int srA = r0 + w*16 + (l >> 2);
  const int srB = e0 + w*16 + (l >> 2);

  auto stage = [&](int buf, int kk){
    const int lb = buf*3*4096 + w*512;
    #pragma unroll
    for (int j = 0; j < 2; ++j){
      const size_t ga = (size_t)(srA + j*64)*512 + kk + sgsw;
      const size_t gb = (size_t)(srB + j*64)*512 + kk + sgsw;
      gload16(&Ahi[ga], &smem[lb + 0    + j*2048]);
      gload16(&B1[gb],  &smem[lb + 4096 + j*2048]);
      gload16(&B2[gb],  &smem[lb + 8192 + j*2048]);
    }
  };

  const int rowA = (w >> 1)*64 + lrow;
  const int rowB = (w & 1)*64 + lrow;
  const int kgs  = (kg ^ ((lrow >> 1) & 3)) * 8;

  auto compute = [&](int buf){
    const int bb = buf*3*4096;
    bf16x8 ah[4];
    #pragma unroll
    for (int m = 0; m < 4; ++m)
      ah[m] = *(const bf16x8*)&smem[bb + (rowA + m*16)*32 + kgs];
    #pragma unroll
    for (int n = 0; n < 4; ++n){
      const int rb = (rowB + n*16)*32 + kgs;
      bf16x8 b1 = *(const bf16x8*)&smem[bb + 4096 + rb];
      bf16x8 b2 = *(const bf16x8*)&smem[bb + 8192 + rb];
      #pragma unroll
      for (int m = 0; m < 4; ++m){
        acc[m][n]  = MFMA16(ah[m], b1, acc[m][n]);
        acc2[m][n] = MFMA16(ah[m], b2, acc2[m][n]);
      }
    }
  };

  stage(0, 0);
  __syncthreads();
  for (int t = 0; t < 16; ++t){
    if (t < 15) stage((t+1) & 1, (t+1)*32);
    compute(t & 1);
    __syncthreads();
  }

  const float* bvv = (job == 3) ? bv1 : bv2;
  const float* bgg = (job == 3) ? bg1 : bg2;
  float* outF = (job == 3) ? vacc1 : vacc2;
  #pragma unroll
  for (int n = 0; n < 4; ++n){
    const int e = e0 + (w & 1)*64 + n*16 + lrow;
    const float bv = bvv[e], bg_ = bgg[e];
    #pragma unroll
    for (int m = 0; m < 4; ++m){
      #pragma unroll
      for (int q = 0; q < 4; ++q){
        const int r = r0 + (w >> 1)*64 + m*16 + kg*4 + q;
        const float yv = acc[m][n][q] + bv;
        const float yg = acc2[m][n][q] + bg_;
        const float sg = 1.0f / (1.0f + exp2f(-yg * LOG2E_F));
        outF[(size_t)r*512 + e] = yv * sg;
      }
    }
  }
}

// ---------------------------------------------------------------------------
// Out projection: 64x128 tile (512 blocks), 2-pass.
// ---------------------------------------------------------------------------
__global__ __launch_bounds__(256,2) void gemmout_kernel(
    const unsigned short* __restrict__ Ahi,
    const unsigned short* __restrict__ Bhi, const unsigned short* __restrict__ Blo,
    const float* __restrict__ bias, float* __restrict__ outF)
{
  __shared__ unsigned short smem[2*10240];
  const int tid = threadIdx.x, w = tid >> 6, l = tid & 63;
  const int r0 = blockIdx.x * 64, e0 = blockIdx.y * 128;
  const int lrow = l & 15, kg = l >> 4;

  f32x4 acc[2][4];
  #pragma unroll
  for (int m = 0; m < 2; ++m)
    #pragma unroll
    for (int n = 0; n < 4; ++n) acc[m][n] = (f32x4){0.f,0.f,0.f,0.f};

  const int sgsw = ((l & 3) ^ ((l >> 3) & 3)) * 8;
  const int srA = r0 + w*16 + (l >> 2);
  const int srB = e0 + w*16 + (l >> 2);

  auto stage = [&](int buf, int kk){
    const int lb = buf*10240;
    gload16(&Ahi[(size_t)srA*512 + kk + sgsw], &smem[lb + tid*8]);
    #pragma unroll
    for (int j = 0; j < 2; ++j){
      const size_t gb = (size_t)(srB + j*64)*512 + kk + sgsw;
      gload16(&Bhi[gb], &smem[lb + 2048 + (tid + j*256)*8]);
      gload16(&Blo[gb], &smem[lb + 6144 + (tid + j*256)*8]);
    }
  };

  const int rowA = (w >> 1)*32 + lrow;
  const int rowB = (w & 1)*64 + lrow;
  const int kgs  = (kg ^ ((lrow >> 1) & 3)) * 8;

  auto compute = [&](int buf){
    const int bb = buf*10240;
    bf16x8 ah[2];
    #pragma unroll
    for (int m = 0; m < 2; ++m)
      ah[m] = *(const bf16x8*)&smem[bb + (rowA + m*16)*32 + kgs];
    #pragma unroll
    for (int n = 0; n < 4; ++n){
      const int rb = (rowB + n*16)*32 + kgs;
      bf16x8 bh = *(const bf16x8*)&smem[bb + 2048 + rb];
      bf16x8 bl = *(const bf16x8*)&smem[bb + 6144 + rb];
      #pragma unroll
      for (int m = 0; m < 2; ++m){
        acc[m][n] = MFMA16(ah[m], bh, acc[m][n]);
        acc[m][n] = MFMA16(ah[m], bl, acc[m][n]);
      }
    }
  };

  stage(0, 0);
  __syncthreads();
  for (int t = 0; t < 16; ++t){
    if (t < 15) stage((t+1) & 1, (t+1)*32);
    compute(t & 1);
    __syncthreads();
  }

  #pragma unroll
  for (int n = 0; n < 4; ++n){
    const int e = e0 + (w & 1)*64 + n*16 + lrow;
    const float bv = bias[e];
    #pragma unroll
    for (int m = 0; m < 2; ++m){
      #pragma unroll
      for (int q = 0; q < 4; ++q){
        const int r = r0 + (w >> 1)*32 + m*16 + kg*4 + q;
        outF[(size_t)r*512 + e] = acc[m][n][q] + bv;
      }
    }
  }
}

// ---------------------------------------------------------------------------
// Per-(bh,t): ll=|q|^2 and packed {cross, aa, 2va, vv} (fp32)
// ---------------------------------------------------------------------------
__global__ __launch_bounds__(256) void norms_kernel(
    const unsigned short* __restrict__ qh, const unsigned short* __restrict__ ql,
    const unsigned short* __restrict__ k1h, const unsigned short* __restrict__ k1l,
    const unsigned short* __restrict__ k2h, const unsigned short* __restrict__ k2l,
    float* __restrict__ ll, f32x4* __restrict__ nrm4)
{
  const int idx = blockIdx.x*256 + threadIdx.x;
  const size_t base = (size_t)idx * 64;
  float sll = 0.f, svv = 0.f, saa = 0.f, sva = 0.f;
  #pragma unroll
  for (int j = 0; j < 8; ++j){
    bf16x8 q_h = *(const bf16x8*)&qh[base + j*8];
    bf16x8 q_l = *(const bf16x8*)&ql[base + j*8];
    bf16x8 a_h = *(const bf16x8*)&k1h[base + j*8];
    bf16x8 a_l = *(const bf16x8*)&k1l[base + j*8];
    bf16x8 c_h = *(const bf16x8*)&k2h[base + j*8];
    bf16x8 c_l = *(const bf16x8*)&k2l[base + j*8];
    #pragma unroll
    for (int i = 0; i < 8; ++i){
      float qv = b2f((unsigned short)q_h[i]) + b2f((unsigned short)q_l[i]);
      float a1 = b2f((unsigned short)a_h[i]) + b2f((unsigned short)a_l[i]);
      float a2 = b2f((unsigned short)c_h[i]) + b2f((unsigned short)c_l[i]);
      sll += qv*qv; svv += a1*a1; saa += a2*a2; sva += a1*a2;
    }
  }
  ll[idx] = sll;
  nrm4[idx] = (f32x4){svv*saa - sva*sva, saa, 2.0f*sva, svv};
}

// ---------------------------------------------------------------------------
// (vacc1 + vacc2) fp32 [r][e] -> transposed bf16 vT[bh][d][s]
// ---------------------------------------------------------------------------
__global__ __launch_bounds__(256) void vtrans_kernel(
    const float* __restrict__ v1, const float* __restrict__ v2,
    unsigned short* __restrict__ vTh)
{
  __shared__ unsigned short sH[64*64];
  const int bh = blockIdx.y, b = bh >> 3, h = bh & 7;
  const int s0 = blockIdx.x * 64;
  const int tid = threadIdx.x;
  for (int c = tid; c < 1024; c += 256){
    const int i = c >> 4, sl = c & 15;
    const size_t g = ((size_t)(s0 + i)*8 + b)*512 + h*64 + sl*4;
    f32x4 a = *(const f32x4*)&v1[g];
    f32x4 bb = *(const f32x4*)&v2[g];
    #pragma unroll
    for (int e = 0; e < 4; ++e)
      sH[(sl*4 + e)*64 + i] = f2b(a[e] + bb[e]);
  }
  __syncthreads();
  for (int c = tid; c < 512; c += 256){
    const int d = c >> 3, sl = c & 7;
    const size_t g = ((size_t)bh*64 + d)*1024 + s0 + sl*8;
    *(bf16x8*)&vTh[g] = *(const bf16x8*)&sH[d*64 + sl*8];
  }
}

// ---------------------------------------------------------------------------
// Fused gram-det attention. QBLK=128 (4 waves x 32 rows), KVBLK=64.
// 1-D grid 512, XCD-swizzled: bh = blk & 63.  setprio around MFMA clusters.
// ---------------------------------------------------------------------------
__global__ __launch_bounds__(256,2) void attn_kernel(
    const unsigned short* __restrict__ qhh, const unsigned short* __restrict__ qhl,
    const unsigned short* __restrict__ k1hh, const unsigned short* __restrict__ k1hl,
    const unsigned short* __restrict__ k2hh, const unsigned short* __restrict__ k2hl,
    const unsigned short* __restrict__ vTh,
    const float* __restrict__ llv, const f32x4* __restrict__ nrm4,
    unsigned short* __restrict__ aoHi)
{
  __shared__ unsigned short sK1h[4096];
  __shared__ unsigned short sK1l[4096];
  __shared__ unsigned short sK2h[4096];
  __shared__ unsigned short sK2l[4096];
  __shared__ unsigned short sVh[4096];
  __shared__ unsigned short sPh[8192];
  __shared__ f32x4 sN4[64];

  const int bh = blockIdx.x & 63, l0 = (blockIdx.x >> 6) * 128;
  const int tid = threadIdx.x, w = tid >> 6, lane = tid & 63;
  const int lrow = lane & 15, kg = lane >> 4;

  bf16x8 qfh[2][2], qfl[2][2];
  #pragma unroll
  for (int m = 0; m < 2; ++m){
    const size_t qb = ((size_t)bh*1024 + l0 + w*32 + m*16 + lrow)*64 + kg*8;
    qfh[m][0] = *(const bf16x8*)&qhh[qb];
    qfl[m][0] = *(const bf16x8*)&qhl[qb];
    qfh[m][1] = *(const bf16x8*)&qhh[qb + 32];
    qfl[m][1] = *(const bf16x8*)&qhl[qb + 32];
  }
  float ll_r[2][4];
  #pragma unroll
  for (int m = 0; m < 2; ++m)
    #pragma unroll
    for (int q = 0; q < 4; ++q)
      ll_r[m][q] = llv[bh*1024 + l0 + w*32 + m*16 + kg*4 + q];

  f32x4 accO[2][4];
  #pragma unroll
  for (int m = 0; m < 2; ++m)
    #pragma unroll
    for (int i = 0; i < 4; ++i) accO[m][i] = (f32x4){0.f,0.f,0.f,0.f};
  float mn[2][4], s_run[2][4];
  #pragma unroll
  for (int m = 0; m < 2; ++m)
    #pragma unroll
    for (int q = 0; q < 4; ++q){ mn[m][q] = 1e30f; s_run[m][q] = 0.f; }

  const int c0 = tid, c1 = tid + 256;
  const int r0g = c0 >> 3, g0 = ((c0 & 7) ^ (r0g & 7)) * 8;
  const int r1g = c1 >> 3, g1 = ((c1 & 7) ^ (r1g & 7)) * 8;

  for (int ss = 0; ss < 1024; ss += 64){
    {
      const size_t kb = (size_t)bh*1024 + ss;
      const size_t k0 = (kb + r0g)*64 + g0;
      const size_t k1_ = (kb + r1g)*64 + g1;
      gload16(&k1hh[k0], &sK1h[c0*8]);  gload16(&k1hh[k1_], &sK1h[c1*8]);
      gload16(&k1hl[k0], &sK1l[c0*8]);  gload16(&k1hl[k1_], &sK1l[c1*8]);
      gload16(&k2hh[k0], &sK2h[c0*8]);  gload16(&k2hh[k1_], &sK2h[c1*8]);
      gload16(&k2hl[k0], &sK2l[c0*8]);  gload16(&k2hl[k1_], &sK2l[c1*8]);
      const size_t v0 = ((size_t)bh*64 + r0g)*1024 + ss + g0;
      const size_t v1 = ((size_t)bh*64 + r1g)*1024 + ss + g1;
      gload16(&vTh[v0], &sVh[c0*8]);    gload16(&vTh[v1], &sVh[c1*8]);
      if (tid < 64) gload16(&nrm4[(size_t)bh*1024 + ss + tid], &sN4[tid]);
    }
    __syncthreads();

    float p_[2][4][4];
    float tmn[2][4];
    #pragma unroll
    for (int m = 0; m < 2; ++m)
      #pragma unroll
      for (int q = 0; q < 4; ++q) tmn[m][q] = 1e30f;

    #pragma unroll
    for (int nt = 0; nt < 4; ++nt){
      f32x4 lv[2], la[2];
      #pragma unroll
      for (int m = 0; m < 2; ++m){ lv[m] = (f32x4){0.f,0.f,0.f,0.f}; la[m] = (f32x4){0.f,0.f,0.f,0.f}; }
      __builtin_amdgcn_s_setprio(1);
      #pragma unroll
      for (int ks = 0; ks < 2; ++ks){
        const int row = nt*16 + lrow;
        const int off = row*64 + (((ks*4 + kg) ^ (row & 7)) * 8);
        bf16x8 b1h = *(const bf16x8*)&sK1h[off];
        bf16x8 b1l = *(const bf16x8*)&sK1l[off];
        bf16x8 b2h = *(const bf16x8*)&sK2h[off];
        bf16x8 b2l = *(const bf16x8*)&sK2l[off];
        #pragma unroll
        for (int m = 0; m < 2; ++m){
          lv[m] = MFMA16(qfh[m][ks], b1h, lv[m]);
          lv[m] = MFMA16(qfh[m][ks], b1l, lv[m]);
          lv[m] = MFMA16(qfl[m][ks], b1h, lv[m]);
          la[m] = MFMA16(qfh[m][ks], b2h, la[m]);
          la[m] = MFMA16(qfh[m][ks], b2l, la[m]);
          la[m] = MFMA16(qfl[m][ks], b2h, la[m]);
        }
      }
      __builtin_amdgcn_s_setprio(0);
      f32x4 n4 = sN4[nt*16 + lrow];
      const float cross = n4[0], c_aa = n4[1], c_va2 = n4[2], c_vv = n4[3];
      #pragma unroll
      for (int m = 0; m < 2; ++m){
        #pragma unroll
        for (int q = 0; q < 4; ++q){
          const float flv = lv[m][q], fla = la[m][q];
          float t = fmaf(-c_vv, fla*fla, (flv*fla)*c_va2);
          t = fmaf(-c_aa, flv*flv, t);
          const float det = fmaf(ll_r[m][q], cross, t);
          const float sq = __builtin_amdgcn_sqrtf(fmaxf(det, EPS_SCALED));
          p_[m][nt][q] = sq;
          tmn[m][q] = fminf(tmn[m][q], sq);
        }
      }
    }
    #pragma unroll
    for (int m = 0; m < 2; ++m)
      #pragma unroll
      for (int q = 0; q < 4; ++q){
        tmn[m][q] = fminf(tmn[m][q], __shfl_xor(tmn[m][q], 1));
        tmn[m][q] = fminf(tmn[m][q], __shfl_xor(tmn[m][q], 2));
        tmn[m][q] = fminf(tmn[m][q], __shfl_xor(tmn[m][q], 4));
        tmn[m][q] = fminf(tmn[m][q], __shfl_xor(tmn[m][q], 8));
      }
    int up = 0;
    #pragma unroll
    for (int m = 0; m < 2; ++m)
      #pragma unroll
      for (int q = 0; q < 4; ++q) up |= (tmn[m][q] < mn[m][q] - DEFER_THR) ? 1 : 0;
    if (__any(up)){
      #pragma unroll
      for (int m = 0; m < 2; ++m)
        #pragma unroll
        for (int q = 0; q < 4; ++q){
          const float mnn = fminf(mn[m][q], tmn[m][q]);
          const float rs = __builtin_amdgcn_exp2f(mnn - mn[m][q]);
          mn[m][q] = mnn;
          s_run[m][q] *= rs;
          #pragma unroll
          for (int dt = 0; dt < 4; ++dt) accO[m][dt][q] *= rs;
        }
    }
    float ps[2][4];
    #pragma unroll
    for (int m = 0; m < 2; ++m)
      #pragma unroll
      for (int q = 0; q < 4; ++q) ps[m][q] = 0.f;
    #pragma unroll
    for (int nt = 0; nt < 4; ++nt)
      #pragma unroll
      for (int m = 0; m < 2; ++m)
        #pragma unroll
        for (int q = 0; q < 4; ++q){
          const float e = __builtin_amdgcn_exp2f(mn[m][q] - p_[m][nt][q]);
          p_[m][nt][q] = e;
          ps[m][q] += e;
        }
    #pragma unroll
    for (int m = 0; m < 2; ++m)
      #pragma unroll
      for (int q = 0; q < 4; ++q){
        float v = ps[m][q];
        v += __shfl_xor(v, 1); v += __shfl_xor(v, 2);
        v += __shfl_xor(v, 4); v += __shfl_xor(v, 8);
        s_run[m][q] += v;
      }

    #pragma unroll
    for (int m = 0; m < 2; ++m){
      #pragma unroll
      for (int nt = 0; nt < 4; ++nt){
        const int col = nt*16 + lrow;
        const int cg = col >> 3, cr = col & 7;
        #pragma unroll
        for (int qp = 0; qp < 2; ++qp){
          unsigned int pk;
          asm("v_cvt_pk_bf16_f32 %0, %1, %2" : "=v"(pk)
              : "v"(p_[m][nt][qp*2]), "v"(p_[m][nt][qp*2+1]));
          const int ra = m*16 + kg*4 + qp*2, rb = ra + 1;
          sPh[w*2048 + ra*64 + ((cg ^ (ra & 7))*8) + cr] = (unsigned short)(pk & 0xffffu);
          sPh[w*2048 + rb*64 + ((cg ^ (rb & 7))*8) + cr] = (unsigned short)(pk >> 16);
        }
      }
    }

    __builtin_amdgcn_s_setprio(1);
    #pragma unroll
    for (int ks = 0; ks < 2; ++ks){
      bf16x8 pa[2];
      #pragma unroll
      for (int m = 0; m < 2; ++m){
        const int prow = m*16 + lrow;
        pa[m] = *(const bf16x8*)&sPh[w*2048 + prow*64 + (((ks*4 + kg) ^ (prow & 7))*8)];
      }
      #pragma unroll
      for (int dt = 0; dt < 4; ++dt){
        const int vrow = dt*16 + lrow;
        bf16x8 bvh = *(const bf16x8*)&sVh[vrow*64 + (((ks*4 + kg) ^ (vrow & 7))*8)];
        #pragma unroll
        for (int m = 0; m < 2; ++m)
          accO[m][dt] = MFMA16(pa[m], bvh, accO[m][dt]);
      }
    }
    __builtin_amdgcn_s_setprio(0);
    __syncthreads();
  }

  const int b = bh >> 3, h = bh & 7;
  #pragma unroll
  for (int m = 0; m < 2; ++m){
    float rcp[4];
    #pragma unroll
    for (int q = 0; q < 4; ++q) rcp[q] = __builtin_amdgcn_rcpf(s_run[m][q]);
    #pragma unroll
    for (int dt = 0; dt < 4; ++dt){
      const int d = dt*16 + lrow;
      #pragma unroll
      for (int q = 0; q < 4; ++q){
        const int l_ = l0 + w*32 + m*16 + kg*4 + q;
        aoHi[((size_t)l_*8 + b)*512 + h*64 + d] = f2b(accO[m][dt][q] * rcp[q]);
      }
    }
  }
}

// ===========================================================================
extern "C" void kernel_launch(void* const* d_in, const int* in_sizes, int n_in,
                              void* d_out, int out_size, void* d_ws, size_t ws_size,
                              hipStream_t stream)
{
  const float* query = (const float*)d_in[0];
  const float* mod1  = (const float*)d_in[1];
  const float* mod2  = (const float*)d_in[2];
  const float* bq  = (const float*)d_in[4];
  const float* bk1 = (const float*)d_in[6];
  const float* bk2 = (const float*)d_in[8];
  const float* bv1 = (const float*)d_in[10];
  const float* bv2 = (const float*)d_in[12];
  const float* bg1 = (const float*)d_in[14];
  const float* bg2 = (const float*)d_in[16];
  const float* bo  = (const float*)d_in[18];

  char* p = (char*)d_ws;
  auto take = [&](size_t bytes) -> char* {
    char* r = p; p += (bytes + 255) & ~(size_t)255; return r;
  };
  const size_t NX = (size_t)8192*512;
  const size_t NW = (size_t)512*512;
  const size_t XB = NX*2, WB = NW*2;
  const size_t HB = (size_t)64*1024*64*2;
  const size_t FB = NX*4;
  const size_t NB = (size_t)64*1024*4;

  unsigned short* xhi = (unsigned short*)take(3*XB);
  unsigned short* whi = (unsigned short*)take(8*WB);
  unsigned short* wlo = (unsigned short*)take(8*WB);
  unsigned short* qh_hi  = (unsigned short*)take(HB);
  unsigned short* qh_lo  = (unsigned short*)take(HB);
  unsigned short* k1h_hi = (unsigned short*)take(HB);
  unsigned short* k1h_lo = (unsigned short*)take(HB);
  unsigned short* k2h_hi = (unsigned short*)take(HB);
  unsigned short* k2h_lo = (unsigned short*)take(HB);
  unsigned short* vT_hi  = (unsigned short*)take(HB);
  float* vacc1 = (float*)take(FB);
  float* vacc2 = (float*)take(FB);
  unsigned short* ao_hi = (unsigned short*)take(HB);
  float* llv = (float*)take(NB);
  f32x4* nrm4 = (f32x4*)take(4*NB);

  // ---- 1. casts / splits ----
  cast3_kernel<<<dim3(2048,3), 256, 0, stream>>>(query, mod1, mod2, xhi, (int)NX);
  splitW_kernel<<<dim3(256,8), 256, 0, stream>>>(
      (const float*)d_in[3], (const float*)d_in[5], (const float*)d_in[7],
      (const float*)d_in[9], (const float*)d_in[11], (const float*)d_in[13],
      (const float*)d_in[15], (const float*)d_in[17], whi, wlo, (int)NW);

  // ---- 2. projections ----
  proj_qk_kernel<<<dim3(64, 12), 256, 0, stream>>>(
      xhi, whi, wlo, bq, bk1, bk2,
      qh_hi, qh_lo, k1h_hi, k1h_lo, k2h_hi, k2h_lo);
  proj_vg_kernel<<<dim3(64, 8), 256, 0, stream>>>(
      xhi, whi, bv1, bg1, bv2, bg2, vacc1, vacc2);

  // ---- 3. gram scalars + gated-V transpose ----
  norms_kernel<<<256, 256, 0, stream>>>(qh_hi, qh_lo, k1h_hi, k1h_lo,
                                        k2h_hi, k2h_lo, llv, nrm4);
  vtrans_kernel<<<dim3(16, 64), 256, 0, stream>>>(vacc1, vacc2, vT_hi);

  // ---- 4. fused gram-det attention ----
  attn_kernel<<<512, 256, 0, stream>>>(
      qh_hi, qh_lo, k1h_hi, k1h_lo, k2h_hi, k2h_lo, vT_hi,
      llv, nrm4, ao_hi);

  // ---- 5. output projection -> d_out ----
  gemmout_kernel<<<dim3(128, 4), 256, 0, stream>>>(
      ao_hi, whi + 7*NW, wlo + 7*NW, bo, (float*)d_out);
}